// Round 12
// baseline (604.573 us; speedup 1.0000x reference)
//
#include <hip/hip_runtime.h>
#include <hip/hip_bf16.h>

// ---------------------------------------------------------------------------
// GCN via device-built CSR (no f32 atomics), all inter-kernel tensors bf16.
// Front:  mega0=[gemm1_lo | deg]  scan  mega1=[gemm1_hi | CSR fill]
// Middle: row-local pipelining of the dependent chain with hw ping-pong:
//   agg1_lo -> [gemm2_lo | agg1_hi] -> gemm2_hi -> agg2_lo ->
//   [gemm3_lo | agg2_hi] -> gemm3_hi -> agg3_lo -> [final_lo | agg3_hi]
//   -> final_hi
// (gemm rows [n0,n0+128) read only hcat rows [n0,n0+128) => gemm_lo legal
//  after agg_lo; agg gathers random rows => needs gemm complete => ping-pong
//  hwA/hwB so a gemm never overwrites the buffer the concurrent agg reads.)
// GEMMs: K=32 LDS chunks, A-stream reg prefetch, W direct to LDS,
// __launch_bounds__(256,2) = 128-VGPR cap = spill-free (arg>=3 spills).
// ---------------------------------------------------------------------------

__device__ __forceinline__ unsigned short f2bf(float f) {  // RNE f32->bf16
  unsigned int u = __float_as_uint(f);
  u += 0x7FFFu + ((u >> 16) & 1u);
  return (unsigned short)(u >> 16);
}
__device__ __forceinline__ unsigned int bfpack(float a, float b) {
  return ((unsigned int)f2bf(a)) | ((unsigned int)f2bf(b) << 16);
}
__device__ __forceinline__ void bf4_unpack(uint2 v, float* f) {
  f[0] = __uint_as_float(v.x << 16); f[1] = __uint_as_float(v.x & 0xFFFF0000u);
  f[2] = __uint_as_float(v.y << 16); f[3] = __uint_as_float(v.y & 0xFFFF0000u);
}
__device__ __forceinline__ void bf8_unpack(uint4 v, float* f) {
  f[0] = __uint_as_float(v.x << 16); f[1] = __uint_as_float(v.x & 0xFFFF0000u);
  f[2] = __uint_as_float(v.y << 16); f[3] = __uint_as_float(v.y & 0xFFFF0000u);
  f[4] = __uint_as_float(v.z << 16); f[5] = __uint_as_float(v.z & 0xFFFF0000u);
  f[6] = __uint_as_float(v.w << 16); f[7] = __uint_as_float(v.w & 0xFFFF0000u);
}

// ---- GEMM body, f32 A (layer 1: A = x) -> hw bf16 -------------------------
__device__ __forceinline__ void gemm128_f32(
    const float* __restrict__ A, long long lda,
    const float* __restrict__ W, unsigned short* __restrict__ hw, int N, int n0,
    float (*hsT)[128], float (*Ws)[128]) {
  const int tid = threadIdx.x;
  const int rows = min(128, N - n0);
  const int tc4 = (tid & 15) << 2;
  const int tr = (tid >> 4) << 3;
  float acc[8][8] = {};
  float4 pa[4];

  auto loadA = [&](int kc) {
    #pragma unroll
    for (int u = 0; u < 4; ++u) {
      const int i = tid + 256 * u;
      const int r = i >> 3, k4 = (i & 7) << 2;
      float4 v = make_float4(0.f, 0.f, 0.f, 0.f);
      if (r < rows) v = *(const float4*)(A + (size_t)(n0 + r) * lda + kc + k4);
      pa[u] = v;
    }
  };
  auto stageA = [&]() {
    #pragma unroll
    for (int u = 0; u < 4; ++u) {
      const int i = tid + 256 * u;
      const int r = i >> 3, k4 = (i & 7) << 2;
      const int c = r ^ k4;
      hsT[k4 + 0][c] = pa[u].x; hsT[k4 + 1][c] = pa[u].y;
      hsT[k4 + 2][c] = pa[u].z; hsT[k4 + 3][c] = pa[u].w;
    }
  };
  auto stageW = [&](int kc) {
    #pragma unroll
    for (int u = 0; u < 4; ++u) {
      const int i = tid + 256 * u;
      const int k = i >> 5, c = (i & 31) << 2;
      *(float4*)&Ws[k][c] = *(const float4*)(W + (size_t)(kc + k) * 128 + c);
    }
  };

  loadA(0);
  for (int kc = 0; kc < 128; kc += 32) {
    stageW(kc);
    stageA();
    __syncthreads();
    if (kc + 32 < 128) loadA(kc + 32);
    #pragma unroll
    for (int k = 0; k < 32; ++k) {
      const int s = k & 28;
      const float4 a0 = *(const float4*)&hsT[k][tr ^ s];
      const float4 a1 = *(const float4*)&hsT[k][(tr + 4) ^ s];
      const float4 w0 = *(const float4*)&Ws[k][tc4];
      const float4 w1 = *(const float4*)&Ws[k][tc4 + 64];
      const float a[8] = {a0.x, a0.y, a0.z, a0.w, a1.x, a1.y, a1.z, a1.w};
      const float w[8] = {w0.x, w0.y, w0.z, w0.w, w1.x, w1.y, w1.z, w1.w};
      #pragma unroll
      for (int i = 0; i < 8; ++i)
        #pragma unroll
        for (int j = 0; j < 8; ++j) acc[i][j] = fmaf(a[i], w[j], acc[i][j]);
    }
    __syncthreads();
  }

  #pragma unroll
  for (int i = 0; i < 8; ++i) {
    const int r = tr + i;
    if (r < rows) {
      unsigned short* hwp = hw + (size_t)(n0 + r) * 128;
      ushort4 o0, o1;
      o0.x = f2bf(acc[i][0]); o0.y = f2bf(acc[i][1]);
      o0.z = f2bf(acc[i][2]); o0.w = f2bf(acc[i][3]);
      o1.x = f2bf(acc[i][4]); o1.y = f2bf(acc[i][5]);
      o1.z = f2bf(acc[i][6]); o1.w = f2bf(acc[i][7]);
      *(ushort4*)(hwp + tc4) = o0;
      *(ushort4*)(hwp + tc4 + 64) = o1;
    }
  }
}

// ---- GEMM body, bf16 A (layers 2,3) -> hw bf16 ----------------------------
__device__ __forceinline__ void gemm128_bf16(
    const unsigned short* __restrict__ A, long long lda,
    const float* __restrict__ W, unsigned short* __restrict__ hw, int nend, int n0,
    float (*hsT)[128], float (*Ws)[128]) {
  const int tid = threadIdx.x;
  const int rows = min(128, nend - n0);
  const int tc4 = (tid & 15) << 2;
  const int tr = (tid >> 4) << 3;
  float acc[8][8] = {};
  uint4 pa[2];

  auto loadA = [&](int kc) {
    #pragma unroll
    for (int u = 0; u < 2; ++u) {
      const int i = tid + 256 * u;
      const int r = i >> 2, k8 = (i & 3) << 3;
      uint4 v = make_uint4(0u, 0u, 0u, 0u);
      if (r < rows) v = *(const uint4*)(A + (size_t)(n0 + r) * lda + kc + k8);
      pa[u] = v;
    }
  };
  auto stageA = [&]() {
    #pragma unroll
    for (int u = 0; u < 2; ++u) {
      const int i = tid + 256 * u;
      const int r = i >> 2, k8 = (i & 3) << 3;
      float f[8];
      bf8_unpack(pa[u], f);
      #pragma unroll
      for (int t = 0; t < 4; ++t) {
        const int k = k8 + 2 * t;
        const int c = r ^ (k & 28);
        hsT[k][c] = f[2 * t];
        hsT[k + 1][c] = f[2 * t + 1];
      }
    }
  };
  auto stageW = [&](int kc) {
    #pragma unroll
    for (int u = 0; u < 4; ++u) {
      const int i = tid + 256 * u;
      const int k = i >> 5, c = (i & 31) << 2;
      *(float4*)&Ws[k][c] = *(const float4*)(W + (size_t)(kc + k) * 128 + c);
    }
  };

  loadA(0);
  for (int kc = 0; kc < 128; kc += 32) {
    stageW(kc);
    stageA();
    __syncthreads();
    if (kc + 32 < 128) loadA(kc + 32);
    #pragma unroll
    for (int k = 0; k < 32; ++k) {
      const int s = k & 28;
      const float4 a0 = *(const float4*)&hsT[k][tr ^ s];
      const float4 a1 = *(const float4*)&hsT[k][(tr + 4) ^ s];
      const float4 w0 = *(const float4*)&Ws[k][tc4];
      const float4 w1 = *(const float4*)&Ws[k][tc4 + 64];
      const float a[8] = {a0.x, a0.y, a0.z, a0.w, a1.x, a1.y, a1.z, a1.w};
      const float w[8] = {w0.x, w0.y, w0.z, w0.w, w1.x, w1.y, w1.z, w1.w};
      #pragma unroll
      for (int i = 0; i < 8; ++i)
        #pragma unroll
        for (int j = 0; j < 8; ++j) acc[i][j] = fmaf(a[i], w[j], acc[i][j]);
    }
    __syncthreads();
  }

  #pragma unroll
  for (int i = 0; i < 8; ++i) {
    const int r = tr + i;
    if (r < rows) {
      unsigned short* hwp = hw + (size_t)(n0 + r) * 128;
      ushort4 o0, o1;
      o0.x = f2bf(acc[i][0]); o0.y = f2bf(acc[i][1]);
      o0.z = f2bf(acc[i][2]); o0.w = f2bf(acc[i][3]);
      o1.x = f2bf(acc[i][4]); o1.y = f2bf(acc[i][5]);
      o1.z = f2bf(acc[i][6]); o1.w = f2bf(acc[i][7]);
      *(ushort4*)(hwp + tc4) = o0;
      *(ushort4*)(hwp + tc4 + 64) = o1;
    }
  }
}

// ---- agg body (32 lanes/node, ushort4/lane, 8-deep gather), node range ----
__device__ __forceinline__ void agg_body(
    int bid, const int* __restrict__ offs, const int* __restrict__ degi,
    const int* __restrict__ sorted_row, const float* __restrict__ dinv,
    const unsigned short* __restrict__ hw, const float* __restrict__ bias,
    unsigned short* __restrict__ hcat, int koff, int nb, int ne) {
  const int g = nb + (int)(((long long)bid * 256 + threadIdx.x) >> 5);
  if (g >= ne) return;
  const int j = (threadIdx.x & 31) << 2;
  const float dc = dinv[g];
  float acc[4];
  {
    const uint2 sv = *(const uint2*)(hw + (size_t)g * 128 + j);
    float f[4];
    bf4_unpack(sv, f);
    #pragma unroll
    for (int q = 0; q < 4; ++q) acc[q] = dc * f[q];
  }

  const int off = offs[g];
  const int end = off + degi[g];
  int e = off;
  for (; e + 7 < end; e += 8) {
    int r[8];
    #pragma unroll
    for (int t = 0; t < 8; ++t) r[t] = sorted_row[e + t];
    float dr[8];
    uint2 v[8];
    #pragma unroll
    for (int t = 0; t < 8; ++t) {
      dr[t] = dinv[r[t]];
      v[t] = *(const uint2*)(hw + (size_t)r[t] * 128 + j);
    }
    #pragma unroll
    for (int t = 0; t < 8; ++t) {
      float f[4];
      bf4_unpack(v[t], f);
      #pragma unroll
      for (int q = 0; q < 4; ++q) acc[q] = fmaf(dr[t], f[q], acc[q]);
    }
  }
  for (; e + 3 < end; e += 4) {
    int r[4];
    #pragma unroll
    for (int t = 0; t < 4; ++t) r[t] = sorted_row[e + t];
    float dr[4];
    uint2 v[4];
    #pragma unroll
    for (int t = 0; t < 4; ++t) {
      dr[t] = dinv[r[t]];
      v[t] = *(const uint2*)(hw + (size_t)r[t] * 128 + j);
    }
    #pragma unroll
    for (int t = 0; t < 4; ++t) {
      float f[4];
      bf4_unpack(v[t], f);
      #pragma unroll
      for (int q = 0; q < 4; ++q) acc[q] = fmaf(dr[t], f[q], acc[q]);
    }
  }
  for (; e < end; ++e) {
    const int r0 = sorted_row[e];
    const float d0 = dinv[r0];
    const uint2 v0 = *(const uint2*)(hw + (size_t)r0 * 128 + j);
    float f[4];
    bf4_unpack(v0, f);
    #pragma unroll
    for (int q = 0; q < 4; ++q) acc[q] = fmaf(d0, f[q], acc[q]);
  }

  const float4 bb = *(const float4*)(bias + j);
  const float o0 = fmaxf(fmaf(dc, acc[0], bb.x), 0.f);
  const float o1 = fmaxf(fmaf(dc, acc[1], bb.y), 0.f);
  const float o2 = fmaxf(fmaf(dc, acc[2], bb.z), 0.f);
  const float o3 = fmaxf(fmaf(dc, acc[3], bb.w), 0.f);
  uint2 st;
  st.x = bfpack(o0, o1);
  st.y = bfpack(o2, o3);
  *(uint2*)(hcat + (size_t)g * 384 + koff + j) = st;
}

// ---- final body (bf16 hcat @ Wlin + blin), row-block goff -----------------
__device__ __forceinline__ void final_body(
    int bid, const unsigned short* __restrict__ hcat,
    const float* __restrict__ Wlin, const float* __restrict__ blin,
    float* __restrict__ out, int goff, int nend,
    float (*hsT)[128], float (*Ws)[64]) {
  const int tid = threadIdx.x;
  const int n0 = (goff + bid) * 128;
  const int rows = min(128, nend - n0);
  const int tc = (tid & 15) << 2;
  const int tr = (tid >> 4) << 3;
  float acc[8][4] = {};
  uint4 pa[2];

  auto loadA = [&](int kc) {
    #pragma unroll
    for (int u = 0; u < 2; ++u) {
      const int i = tid + 256 * u;
      const int r = i >> 2, k8 = (i & 3) << 3;
      uint4 v = make_uint4(0u, 0u, 0u, 0u);
      if (r < rows) v = *(const uint4*)(hcat + (size_t)(n0 + r) * 384 + kc + k8);
      pa[u] = v;
    }
  };
  auto stageA = [&]() {
    #pragma unroll
    for (int u = 0; u < 2; ++u) {
      const int i = tid + 256 * u;
      const int r = i >> 2, k8 = (i & 3) << 3;
      float f[8];
      bf8_unpack(pa[u], f);
      #pragma unroll
      for (int t = 0; t < 4; ++t) {
        const int k = k8 + 2 * t;
        const int c = r ^ (k & 28);
        hsT[k][c] = f[2 * t];
        hsT[k + 1][c] = f[2 * t + 1];
      }
    }
  };
  auto stageW = [&](int kc) {
    #pragma unroll
    for (int u = 0; u < 2; ++u) {
      const int i = tid + 256 * u;
      const int k = i >> 4, c = (i & 15) << 2;
      *(float4*)&Ws[k][c] = *(const float4*)(Wlin + (size_t)(kc + k) * 64 + c);
    }
  };

  loadA(0);
  for (int kc = 0; kc < 384; kc += 32) {
    stageW(kc);
    stageA();
    __syncthreads();
    if (kc + 32 < 384) loadA(kc + 32);
    #pragma unroll
    for (int k = 0; k < 32; ++k) {
      const int s = k & 28;
      const float4 a0 = *(const float4*)&hsT[k][tr ^ s];
      const float4 a1 = *(const float4*)&hsT[k][(tr + 4) ^ s];
      const float4 w0 = *(const float4*)&Ws[k][tc];
      const float a[8] = {a0.x, a0.y, a0.z, a0.w, a1.x, a1.y, a1.z, a1.w};
      const float w[4] = {w0.x, w0.y, w0.z, w0.w};
      #pragma unroll
      for (int i = 0; i < 8; ++i)
        #pragma unroll
        for (int j = 0; j < 4; ++j) acc[i][j] = fmaf(a[i], w[j], acc[i][j]);
    }
    __syncthreads();
  }

  #pragma unroll
  for (int i = 0; i < 8; ++i) {
    const int r = tr + i;
    if (r < rows) {
      const float4 bb = *(const float4*)(blin + tc);
      *(float4*)(out + (size_t)(n0 + r) * 64 + tc) =
          make_float4(acc[i][0] + bb.x, acc[i][1] + bb.y,
                      acc[i][2] + bb.z, acc[i][3] + bb.w);
    }
  }
}

// ---- mega0: [gemm1 lower half | degree count] (gemm blocks first) ---------
__global__ __launch_bounds__(256, 2) void k_mega0(
    const float* __restrict__ x, const float* __restrict__ W1,
    unsigned short* __restrict__ hw, int N, int gb,
    const int* __restrict__ coli, int E, int* __restrict__ degi) {
  __shared__ __align__(16) float hsT[32][128];
  __shared__ __align__(16) float Ws[32][128];
  if ((int)blockIdx.x < gb) {
    gemm128_f32(x, 128, W1, hw, N, blockIdx.x * 128, hsT, Ws);
  } else {
    const int b = blockIdx.x - gb;
    #pragma unroll
    for (int h = 0; h < 2; ++h) {
      const int base = b * 2048 + h * 1024 + (int)threadIdx.x * 4;
      if (base + 3 < E) {
        const int4 c4 = *(const int4*)(coli + base);
        atomicAdd(&degi[c4.x], 1); atomicAdd(&degi[c4.y], 1);
        atomicAdd(&degi[c4.z], 1); atomicAdd(&degi[c4.w], 1);
      } else {
        for (int e = base; e < E; ++e) atomicAdd(&degi[coli[e]], 1);
      }
    }
  }
}

// ---- mega1: [gemm1 upper half | CSR fill] (gemm blocks first) -------------
__global__ __launch_bounds__(256, 2) void k_mega1(
    const float* __restrict__ x, const float* __restrict__ W1,
    unsigned short* __restrict__ hw, int N, int gb, int goff,
    const int* __restrict__ rowi, const int* __restrict__ coli,
    int* __restrict__ cursor, int* __restrict__ sorted_row, int E) {
  __shared__ __align__(16) float hsT[32][128];
  __shared__ __align__(16) float Ws[32][128];
  if ((int)blockIdx.x < gb) {
    gemm128_f32(x, 128, W1, hw, N, (goff + blockIdx.x) * 128, hsT, Ws);
  } else {
    const int b = blockIdx.x - gb;
    const int base = b * 1024 + (int)threadIdx.x * 4;
    if (base + 3 < E) {
      const int4 c4 = *(const int4*)(coli + base);
      const int4 r4 = *(const int4*)(rowi + base);
      int p;
      p = atomicAdd(&cursor[c4.x], 1); __builtin_nontemporal_store(r4.x, &sorted_row[p]);
      p = atomicAdd(&cursor[c4.y], 1); __builtin_nontemporal_store(r4.y, &sorted_row[p]);
      p = atomicAdd(&cursor[c4.z], 1); __builtin_nontemporal_store(r4.z, &sorted_row[p]);
      p = atomicAdd(&cursor[c4.w], 1); __builtin_nontemporal_store(r4.w, &sorted_row[p]);
    } else {
      for (int e = base; e < E; ++e) {
        const int p = atomicAdd(&cursor[coli[e]], 1);
        __builtin_nontemporal_store(rowi[e], &sorted_row[p]);
      }
    }
  }
}

// ---- scan passes ----------------------------------------------------------
__global__ __launch_bounds__(256) void k_scan1(const int* __restrict__ degi, int N,
                                               int* __restrict__ offs,
                                               int* __restrict__ bsums,
                                               float* __restrict__ dinv) {
  __shared__ int sm[256];
  const int b = blockIdx.x, t = threadIdx.x;
  const int base = b * 1024 + t * 4;
  int v[4];
  #pragma unroll
  for (int i = 0; i < 4; ++i) v[i] = (base + i < N) ? degi[base + i] : 0;
  #pragma unroll
  for (int i = 0; i < 4; ++i)
    if (base + i < N) dinv[base + i] = rsqrtf(1.0f + (float)v[i]);
  const int s = v[0] + v[1] + v[2] + v[3];
  sm[t] = s;
  __syncthreads();
  for (int ofs = 1; ofs < 256; ofs <<= 1) {
    const int add = (t >= ofs) ? sm[t - ofs] : 0;
    __syncthreads();
    sm[t] += add;
    __syncthreads();
  }
  if (t == 255) bsums[b] = sm[255];
  int run = sm[t] - s;
  #pragma unroll
  for (int i = 0; i < 4; ++i) {
    if (base + i < N) offs[base + i] = run;
    run += v[i];
  }
}

__global__ __launch_bounds__(128) void k_scan2(int* __restrict__ bsums, int nb) {
  __shared__ int sm[128];
  const int t = threadIdx.x;
  const int v = (t < nb) ? bsums[t] : 0;
  sm[t] = v;
  __syncthreads();
  for (int ofs = 1; ofs < 128; ofs <<= 1) {
    const int add = (t >= ofs) ? sm[t - ofs] : 0;
    __syncthreads();
    sm[t] += add;
    __syncthreads();
  }
  if (t < nb) bsums[t] = sm[t] - v;
}

__global__ __launch_bounds__(256) void k_scan3(int* __restrict__ offs,
                                               const int* __restrict__ bsums,
                                               int* __restrict__ cursor, int N) {
  const int add = bsums[blockIdx.x];
  const int base = blockIdx.x * 1024 + threadIdx.x * 4;
  #pragma unroll
  for (int i = 0; i < 4; ++i) {
    const int idx = base + i;
    if (idx < N) {
      const int o = offs[idx] + add;
      offs[idx] = o;
      cursor[idx] = o;
    }
  }
}

// ---- standalone kernels (range-parameterized) -----------------------------
__global__ __launch_bounds__(256, 2) void k_gemm128(
    const unsigned short* __restrict__ A, long long lda,
    const float* __restrict__ W, unsigned short* __restrict__ hw,
    int goff, int nend) {
  __shared__ __align__(16) float hsT[32][128];
  __shared__ __align__(16) float Ws[32][128];
  gemm128_bf16(A, lda, W, hw, nend, (goff + blockIdx.x) * 128, hsT, Ws);
}

__global__ __launch_bounds__(256) void k_agg(
    const int* __restrict__ offs, const int* __restrict__ degi,
    const int* __restrict__ sorted_row, const float* __restrict__ dinv,
    const unsigned short* __restrict__ hw, const float* __restrict__ bias,
    unsigned short* __restrict__ hcat, int koff, int nb, int ne) {
  agg_body(blockIdx.x, offs, degi, sorted_row, dinv, hw, bias, hcat, koff, nb, ne);
}

__global__ __launch_bounds__(256, 2) void k_final(
    const unsigned short* __restrict__ hcat, const float* __restrict__ Wlin,
    const float* __restrict__ blin, float* __restrict__ out, int goff, int nend) {
  __shared__ __align__(16) float hsT[32][128];
  __shared__ __align__(16) float Ws[32][64];
  final_body(blockIdx.x, hcat, Wlin, blin, out, goff, nend, hsT, Ws);
}

// ---- mix: [gemm (blocks 0..gb) | agg (rest)] ------------------------------
__global__ __launch_bounds__(256, 2) void k_mix_ga(
    const unsigned short* __restrict__ A, long long lda,
    const float* __restrict__ W, unsigned short* __restrict__ hwout, int gend,
    int gb,
    const int* __restrict__ offs, const int* __restrict__ degi,
    const int* __restrict__ sorted_row, const float* __restrict__ dinv,
    const unsigned short* __restrict__ hwin, const float* __restrict__ bias,
    unsigned short* __restrict__ hcat, int koff, int nb, int ne) {
  __shared__ __align__(16) float hsT[32][128];
  __shared__ __align__(16) float Ws[32][128];
  if ((int)blockIdx.x < gb) {
    gemm128_bf16(A, lda, W, hwout, gend, blockIdx.x * 128, hsT, Ws);
  } else {
    agg_body(blockIdx.x - gb, offs, degi, sorted_row, dinv, hwin, bias,
             hcat, koff, nb, ne);
  }
}

// ---- mix: [final (blocks 0..fb) | agg (rest)] -----------------------------
__global__ __launch_bounds__(256, 2) void k_mix_fa(
    const unsigned short* __restrict__ hcat, const float* __restrict__ Wlin,
    const float* __restrict__ blin, float* __restrict__ out, int fend,
    int fb,
    const int* __restrict__ offs, const int* __restrict__ degi,
    const int* __restrict__ sorted_row, const float* __restrict__ dinv,
    const unsigned short* __restrict__ hwin, const float* __restrict__ bias,
    int koff, int nb, int ne) {
  __shared__ __align__(16) float hsT[32][128];
  __shared__ __align__(16) float Ws[32][64];
  if ((int)blockIdx.x < fb) {
    final_body(blockIdx.x, hcat, Wlin, blin, out, 0, fend, hsT, Ws);
  } else {
    agg_body(blockIdx.x - fb, offs, degi, sorted_row, dinv, hwin, bias,
             (unsigned short*)hcat, koff, nb, ne);
  }
}

extern "C" void kernel_launch(void* const* d_in, const int* in_sizes, int n_in,
                              void* d_out, int out_size, void* d_ws, size_t ws_size,
                              hipStream_t stream) {
  const float* x    = (const float*)d_in[0];
  const int*   ei   = (const int*)d_in[1];
  const float* W1   = (const float*)d_in[2];
  const float* b1   = (const float*)d_in[3];
  const float* W2   = (const float*)d_in[4];
  const float* b2   = (const float*)d_in[5];
  const float* W3   = (const float*)d_in[6];
  const float* b3   = (const float*)d_in[7];
  const float* Wlin = (const float*)d_in[8];
  const float* blin = (const float*)d_in[9];

  const int N = in_sizes[0] / 128;
  const int E = in_sizes[1] / 2;
  const int* rowi = ei;
  const int* coli = ei + E;

  // ws: degi | dinv | offs | cursor | bsums | sorted_row | hwA | hwB | hcat
  char* ws = (char*)d_ws;
  const size_t nb4 = (((size_t)N * 4) + 255) & ~(size_t)255;
  int*   degi       = (int*)ws;                 ws += nb4;
  float* dinv       = (float*)ws;               ws += nb4;
  int*   offs       = (int*)ws;                 ws += nb4;
  int*   cursor     = (int*)ws;                 ws += nb4;
  int*   bsums      = (int*)ws;                 ws += 1024;
  int*   sorted_row = (int*)ws;                 ws += (((size_t)E * 4) + 255) & ~(size_t)255;
  unsigned short* hwA  = (unsigned short*)ws;   ws += (size_t)N * 128 * 2;
  unsigned short* hwB  = (unsigned short*)ws;   ws += (size_t)N * 128 * 2;
  unsigned short* hcat = (unsigned short*)ws;

  const int nblk = (N + 1023) / 1024;
  const int gemmBlocks = (N + 127) / 128;
  const int gb0 = gemmBlocks / 2;
  const int gb1 = gemmBlocks - gb0;
  const int degBlocks  = (E + 2047) / 2048;
  const int fillBlocks = (E + 1023) / 1024;

  // pipeline split: half boundary aligned to 128-row GEMM blocks
  const int half = (N / 2) & ~127;
  const int gLo = half / 128;
  const int gHi = gemmBlocks - gLo;
  const int aggLo = (half + 7) / 8;
  const int aggHi = (N - half + 7) / 8;

  hipMemsetAsync(degi, 0, (size_t)N * 4, stream);
  k_mega0<<<gb0 + degBlocks, 256, 0, stream>>>(x, W1, hwA, N, gb0, coli, E, degi);
  k_scan1<<<nblk, 256, 0, stream>>>(degi, N, offs, bsums, dinv);
  k_scan2<<<1, 128, 0, stream>>>(bsums, nblk);
  k_scan3<<<nblk, 256, 0, stream>>>(offs, bsums, cursor, N);
  k_mega1<<<gb1 + fillBlocks, 256, 0, stream>>>(x, W1, hwA, N, gb1, gb0,
                                                rowi, coli, cursor, sorted_row, E);

  // --- layer 1 agg + layer 2 gemm, pipelined in halves (hwA -> hwB) ---
  k_agg<<<aggLo, 256, 0, stream>>>(offs, degi, sorted_row, dinv, hwA,
                                   b1, hcat, 0, 0, half);
  k_mix_ga<<<gLo + aggHi, 256, 0, stream>>>(hcat + 0, 384, W2, hwB, half, gLo,
                                            offs, degi, sorted_row, dinv, hwA,
                                            b1, hcat, 0, half, N);
  k_gemm128<<<gHi, 256, 0, stream>>>(hcat + 0, 384, W2, hwB, gLo, N);

  // --- layer 2 agg + layer 3 gemm (hwB -> hwA) ---
  k_agg<<<aggLo, 256, 0, stream>>>(offs, degi, sorted_row, dinv, hwB,
                                   b2, hcat, 128, 0, half);
  k_mix_ga<<<gLo + aggHi, 256, 0, stream>>>(hcat + 128, 384, W3, hwA, half, gLo,
                                            offs, degi, sorted_row, dinv, hwB,
                                            b2, hcat, 128, half, N);
  k_gemm128<<<gHi, 256, 0, stream>>>(hcat + 128, 384, W3, hwA, gLo, N);

  // --- layer 3 agg + final, pipelined (reads hwA) ---
  k_agg<<<aggLo, 256, 0, stream>>>(offs, degi, sorted_row, dinv, hwA,
                                   b3, hcat, 256, 0, half);
  k_mix_fa<<<gLo + aggHi, 256, 0, stream>>>(hcat, Wlin, blin, (float*)d_out,
                                            half, gLo,
                                            offs, degi, sorted_row, dinv, hwA,
                                            b3, 256, half, N);
  k_final<<<gHi, 256, 0, stream>>>(hcat, Wlin, blin, (float*)d_out, gLo, N);
}

// Round 13
// 495.603 us; speedup vs baseline: 1.2199x; 1.2199x over previous
//
#include <hip/hip_runtime.h>
#include <hip/hip_bf16.h>

// ---------------------------------------------------------------------------
// GCN via device-built CSR (no f32 atomics), all inter-kernel tensors bf16.
// r11 schedule (best) + MFMA for gemm2/3:
//   k_wt: W2,W3 (f32 [k][n]) -> WT bf16 [n][k]   (tiny, no deps)
//   mega0=[gemm1_lo | deg]  scan  mega1=[gemm1_hi | CSR fill]
//   3x [ hw = bf16(hprev @ W) ; agg -> hcat bf16 ]   gemm2/3 via
//   mfma_f32_32x32x16_bf16: full-K LDS staging (32KB A + 32KB WT) with XOR
//   swizzle byte^=(row&7)<<4 (col-of-rows ds_read_b128 else 32-way conflict),
//   4 waves x 4 n-tiles x 8 K-steps; C/D map col=lane&31,
//   row=(reg&3)+8*(reg>>2)+4*(lane>>5)  [m74/m101-verified].
//   out = hcat @ Wlin + blin  (f32 vector path, untouched this round)
// ---------------------------------------------------------------------------

typedef __attribute__((ext_vector_type(8))) short bf16x8;
typedef __attribute__((ext_vector_type(16))) float f32x16;

__device__ __forceinline__ unsigned short f2bf(float f) {  // RNE f32->bf16
  unsigned int u = __float_as_uint(f);
  u += 0x7FFFu + ((u >> 16) & 1u);
  return (unsigned short)(u >> 16);
}
__device__ __forceinline__ unsigned int bfpack(float a, float b) {
  return ((unsigned int)f2bf(a)) | ((unsigned int)f2bf(b) << 16);
}
__device__ __forceinline__ void bf4_unpack(uint2 v, float* f) {
  f[0] = __uint_as_float(v.x << 16); f[1] = __uint_as_float(v.x & 0xFFFF0000u);
  f[2] = __uint_as_float(v.y << 16); f[3] = __uint_as_float(v.y & 0xFFFF0000u);
}
__device__ __forceinline__ void bf8_unpack(uint4 v, float* f) {
  f[0] = __uint_as_float(v.x << 16); f[1] = __uint_as_float(v.x & 0xFFFF0000u);
  f[2] = __uint_as_float(v.y << 16); f[3] = __uint_as_float(v.y & 0xFFFF0000u);
  f[4] = __uint_as_float(v.z << 16); f[5] = __uint_as_float(v.z & 0xFFFF0000u);
  f[6] = __uint_as_float(v.w << 16); f[7] = __uint_as_float(v.w & 0xFFFF0000u);
}

// ---- W transpose: WT[n][k] = bf16(W[k][n]), for W2 and W3 -----------------
__global__ __launch_bounds__(256) void k_wt(
    const float* __restrict__ W2, const float* __restrict__ W3,
    unsigned short* __restrict__ WT2, unsigned short* __restrict__ WT3) {
  const int idx = blockIdx.x * 256 + threadIdx.x;   // 32768 total
  const int w = idx >> 14;
  const int rem = idx & 16383;
  const int n = rem >> 7, k = rem & 127;
  const float* W = w ? W3 : W2;
  unsigned short* WT = w ? WT3 : WT2;
  WT[n * 128 + k] = f2bf(W[k * 128 + n]);
}

// ---- GEMM body, f32 A (layer 1: A = x) -> hw bf16 -------------------------
__device__ __forceinline__ void gemm128_f32(
    const float* __restrict__ A, long long lda,
    const float* __restrict__ W, unsigned short* __restrict__ hw, int N, int n0,
    float (*hsT)[128], float (*Ws)[128]) {
  const int tid = threadIdx.x;
  const int rows = min(128, N - n0);
  const int tc4 = (tid & 15) << 2;
  const int tr = (tid >> 4) << 3;
  float acc[8][8] = {};
  float4 pa[4];

  auto loadA = [&](int kc) {
    #pragma unroll
    for (int u = 0; u < 4; ++u) {
      const int i = tid + 256 * u;
      const int r = i >> 3, k4 = (i & 7) << 2;
      float4 v = make_float4(0.f, 0.f, 0.f, 0.f);
      if (r < rows) v = *(const float4*)(A + (size_t)(n0 + r) * lda + kc + k4);
      pa[u] = v;
    }
  };
  auto stageA = [&]() {
    #pragma unroll
    for (int u = 0; u < 4; ++u) {
      const int i = tid + 256 * u;
      const int r = i >> 3, k4 = (i & 7) << 2;
      const int c = r ^ k4;
      hsT[k4 + 0][c] = pa[u].x; hsT[k4 + 1][c] = pa[u].y;
      hsT[k4 + 2][c] = pa[u].z; hsT[k4 + 3][c] = pa[u].w;
    }
  };
  auto stageW = [&](int kc) {
    #pragma unroll
    for (int u = 0; u < 4; ++u) {
      const int i = tid + 256 * u;
      const int k = i >> 5, c = (i & 31) << 2;
      *(float4*)&Ws[k][c] = *(const float4*)(W + (size_t)(kc + k) * 128 + c);
    }
  };

  loadA(0);
  for (int kc = 0; kc < 128; kc += 32) {
    stageW(kc);
    stageA();
    __syncthreads();
    if (kc + 32 < 128) loadA(kc + 32);
    #pragma unroll
    for (int k = 0; k < 32; ++k) {
      const int s = k & 28;
      const float4 a0 = *(const float4*)&hsT[k][tr ^ s];
      const float4 a1 = *(const float4*)&hsT[k][(tr + 4) ^ s];
      const float4 w0 = *(const float4*)&Ws[k][tc4];
      const float4 w1 = *(const float4*)&Ws[k][tc4 + 64];
      const float a[8] = {a0.x, a0.y, a0.z, a0.w, a1.x, a1.y, a1.z, a1.w};
      const float w[8] = {w0.x, w0.y, w0.z, w0.w, w1.x, w1.y, w1.z, w1.w};
      #pragma unroll
      for (int i = 0; i < 8; ++i)
        #pragma unroll
        for (int j = 0; j < 8; ++j) acc[i][j] = fmaf(a[i], w[j], acc[i][j]);
    }
    __syncthreads();
  }

  #pragma unroll
  for (int i = 0; i < 8; ++i) {
    const int r = tr + i;
    if (r < rows) {
      unsigned short* hwp = hw + (size_t)(n0 + r) * 128;
      ushort4 o0, o1;
      o0.x = f2bf(acc[i][0]); o0.y = f2bf(acc[i][1]);
      o0.z = f2bf(acc[i][2]); o0.w = f2bf(acc[i][3]);
      o1.x = f2bf(acc[i][4]); o1.y = f2bf(acc[i][5]);
      o1.z = f2bf(acc[i][6]); o1.w = f2bf(acc[i][7]);
      *(ushort4*)(hwp + tc4) = o0;
      *(ushort4*)(hwp + tc4 + 64) = o1;
    }
  }
}

// ---- MFMA GEMM (layers 2,3): hw = bf16(A_bf16 @ W) via WT -----------------
__global__ __launch_bounds__(256, 2) void k_gemm_mfma(
    const unsigned short* __restrict__ A, long long lda,
    const unsigned short* __restrict__ WT, unsigned short* __restrict__ hw,
    int N) {
  __shared__ __align__(16) unsigned short hs[128 * 128];   // 32KB, swizzled
  __shared__ __align__(16) unsigned short WsT[128 * 128];  // 32KB, swizzled
  const int tid = threadIdx.x;
  const int n0 = blockIdx.x * 128;
  const int rows = min(128, N - n0);
  char* hsb = (char*)hs;
  char* wsb = (char*)WsT;

  // stage A rows (bf16, [row][k], XOR-swizzled 16B chunks)
  #pragma unroll
  for (int u = 0; u < 8; ++u) {
    const int i = tid + 256 * u;
    const int r = i >> 4, k8 = (i & 15) << 3;
    uint4 v = make_uint4(0u, 0u, 0u, 0u);
    if (r < rows) v = *(const uint4*)(A + (size_t)(n0 + r) * lda + k8);
    *(uint4*)(hsb + ((r * 256 + k8 * 2) ^ ((r & 7) << 4))) = v;
  }
  // stage WT rows ([n][k])
  #pragma unroll
  for (int u = 0; u < 8; ++u) {
    const int i = tid + 256 * u;
    const int nn = i >> 4, k8 = (i & 15) << 3;
    const uint4 v = *(const uint4*)(WT + nn * 128 + k8);
    *(uint4*)(wsb + ((nn * 256 + k8 * 2) ^ ((nn & 7) << 4))) = v;
  }
  __syncthreads();

  const int l = tid & 63;
  const int m0 = (tid >> 6) << 5;      // wave row base (0,32,64,96)
  const int lm = l & 31;
  const int lk = (l >> 5) << 3;        // K sub-offset: 0 or 8
  const int ra = m0 + lm;              // A row this lane reads
  f32x16 acc[4];
  #pragma unroll
  for (int t = 0; t < 4; ++t)
    #pragma unroll
    for (int q = 0; q < 16; ++q) acc[t][q] = 0.f;

  #pragma unroll
  for (int ks = 0; ks < 8; ++ks) {
    const int kb = (ks * 16 + lk) * 2;  // byte offset along K
    const bf16x8 af = *(const bf16x8*)(hsb + ((ra * 256 + kb) ^ ((ra & 7) << 4)));
    #pragma unroll
    for (int t = 0; t < 4; ++t) {
      const int rb = t * 32 + lm;
      const bf16x8 bfr = *(const bf16x8*)(wsb + ((rb * 256 + kb) ^ ((rb & 7) << 4)));
      acc[t] = __builtin_amdgcn_mfma_f32_32x32x16_bf16(af, bfr, acc[t], 0, 0, 0);
    }
  }

  // C/D: col = lane&31 (n within tile), row = (q&3)+8*(q>>2)+4*(lane>>5)
  #pragma unroll
  for (int t = 0; t < 4; ++t) {
    #pragma unroll
    for (int q = 0; q < 16; ++q) {
      const int m = m0 + (q & 3) + ((q >> 2) << 3) + ((l >> 5) << 2);
      if (m < rows) hw[(size_t)(n0 + m) * 128 + t * 32 + lm] = f2bf(acc[t][q]);
    }
  }
}

// ---- mega0: [gemm1 lower half | degree count] (gemm blocks first) ---------
__global__ __launch_bounds__(256, 2) void k_mega0(
    const float* __restrict__ x, const float* __restrict__ W1,
    unsigned short* __restrict__ hw, int N, int gb,
    const int* __restrict__ coli, int E, int* __restrict__ degi) {
  __shared__ __align__(16) float hsT[32][128];
  __shared__ __align__(16) float Ws[32][128];
  if ((int)blockIdx.x < gb) {
    gemm128_f32(x, 128, W1, hw, N, blockIdx.x * 128, hsT, Ws);
  } else {
    const int b = blockIdx.x - gb;
    #pragma unroll
    for (int h = 0; h < 2; ++h) {
      const int base = b * 2048 + h * 1024 + (int)threadIdx.x * 4;
      if (base + 3 < E) {
        const int4 c4 = *(const int4*)(coli + base);
        atomicAdd(&degi[c4.x], 1); atomicAdd(&degi[c4.y], 1);
        atomicAdd(&degi[c4.z], 1); atomicAdd(&degi[c4.w], 1);
      } else {
        for (int e = base; e < E; ++e) atomicAdd(&degi[coli[e]], 1);
      }
    }
  }
}

// ---- mega1: [gemm1 upper half | CSR fill] (gemm blocks first) -------------
__global__ __launch_bounds__(256, 2) void k_mega1(
    const float* __restrict__ x, const float* __restrict__ W1,
    unsigned short* __restrict__ hw, int N, int gb, int goff,
    const int* __restrict__ rowi, const int* __restrict__ coli,
    int* __restrict__ cursor, int* __restrict__ sorted_row, int E) {
  __shared__ __align__(16) float hsT[32][128];
  __shared__ __align__(16) float Ws[32][128];
  if ((int)blockIdx.x < gb) {
    gemm128_f32(x, 128, W1, hw, N, (goff + blockIdx.x) * 128, hsT, Ws);
  } else {
    const int b = blockIdx.x - gb;
    const int base = b * 1024 + (int)threadIdx.x * 4;
    if (base + 3 < E) {
      const int4 c4 = *(const int4*)(coli + base);
      const int4 r4 = *(const int4*)(rowi + base);
      int p;
      p = atomicAdd(&cursor[c4.x], 1); __builtin_nontemporal_store(r4.x, &sorted_row[p]);
      p = atomicAdd(&cursor[c4.y], 1); __builtin_nontemporal_store(r4.y, &sorted_row[p]);
      p = atomicAdd(&cursor[c4.z], 1); __builtin_nontemporal_store(r4.z, &sorted_row[p]);
      p = atomicAdd(&cursor[c4.w], 1); __builtin_nontemporal_store(r4.w, &sorted_row[p]);
    } else {
      for (int e = base; e < E; ++e) {
        const int p = atomicAdd(&cursor[coli[e]], 1);
        __builtin_nontemporal_store(rowi[e], &sorted_row[p]);
      }
    }
  }
}

// ---- scan passes ----------------------------------------------------------
__global__ __launch_bounds__(256) void k_scan1(const int* __restrict__ degi, int N,
                                               int* __restrict__ offs,
                                               int* __restrict__ bsums,
                                               float* __restrict__ dinv) {
  __shared__ int sm[256];
  const int b = blockIdx.x, t = threadIdx.x;
  const int base = b * 1024 + t * 4;
  int v[4];
  #pragma unroll
  for (int i = 0; i < 4; ++i) v[i] = (base + i < N) ? degi[base + i] : 0;
  #pragma unroll
  for (int i = 0; i < 4; ++i)
    if (base + i < N) dinv[base + i] = rsqrtf(1.0f + (float)v[i]);
  const int s = v[0] + v[1] + v[2] + v[3];
  sm[t] = s;
  __syncthreads();
  for (int ofs = 1; ofs < 256; ofs <<= 1) {
    const int add = (t >= ofs) ? sm[t - ofs] : 0;
    __syncthreads();
    sm[t] += add;
    __syncthreads();
  }
  if (t == 255) bsums[b] = sm[255];
  int run = sm[t] - s;
  #pragma unroll
  for (int i = 0; i < 4; ++i) {
    if (base + i < N) offs[base + i] = run;
    run += v[i];
  }
}

__global__ __launch_bounds__(128) void k_scan2(int* __restrict__ bsums, int nb) {
  __shared__ int sm[128];
  const int t = threadIdx.x;
  const int v = (t < nb) ? bsums[t] : 0;
  sm[t] = v;
  __syncthreads();
  for (int ofs = 1; ofs < 128; ofs <<= 1) {
    const int add = (t >= ofs) ? sm[t - ofs] : 0;
    __syncthreads();
    sm[t] += add;
    __syncthreads();
  }
  if (t < nb) bsums[t] = sm[t] - v;
}

__global__ __launch_bounds__(256) void k_scan3(int* __restrict__ offs,
                                               const int* __restrict__ bsums,
                                               int* __restrict__ cursor, int N) {
  const int add = bsums[blockIdx.x];
  const int base = blockIdx.x * 1024 + threadIdx.x * 4;
  #pragma unroll
  for (int i = 0; i < 4; ++i) {
    const int idx = base + i;
    if (idx < N) {
      const int o = offs[idx] + add;
      offs[idx] = o;
      cursor[idx] = o;
    }
  }
}

// ---- segment aggregate (32 lanes/node, ushort4/lane, 8-deep gather) -------
__global__ __launch_bounds__(256) void k_agg(
    const int* __restrict__ offs, const int* __restrict__ degi,
    const int* __restrict__ sorted_row, const float* __restrict__ dinv,
    const unsigned short* __restrict__ hw, const float* __restrict__ bias,
    unsigned short* __restrict__ hcat, int koff, int N) {
  const int g = (int)((blockIdx.x * 256 + threadIdx.x) >> 5);
  if (g >= N) return;
  const int j = (threadIdx.x & 31) << 2;
  const float dc = dinv[g];
  float acc[4];
  {
    const uint2 sv = *(const uint2*)(hw + (size_t)g * 128 + j);
    float f[4];
    bf4_unpack(sv, f);
    #pragma unroll
    for (int q = 0; q < 4; ++q) acc[q] = dc * f[q];
  }

  const int off = offs[g];
  const int end = off + degi[g];
  int e = off;
  for (; e + 7 < end; e += 8) {
    int r[8];
    #pragma unroll
    for (int t = 0; t < 8; ++t) r[t] = sorted_row[e + t];
    float dr[8];
    uint2 v[8];
    #pragma unroll
    for (int t = 0; t < 8; ++t) {
      dr[t] = dinv[r[t]];
      v[t] = *(const uint2*)(hw + (size_t)r[t] * 128 + j);
    }
    #pragma unroll
    for (int t = 0; t < 8; ++t) {
      float f[4];
      bf4_unpack(v[t], f);
      #pragma unroll
      for (int q = 0; q < 4; ++q) acc[q] = fmaf(dr[t], f[q], acc[q]);
    }
  }
  for (; e + 3 < end; e += 4) {
    int r[4];
    #pragma unroll
    for (int t = 0; t < 4; ++t) r[t] = sorted_row[e + t];
    float dr[4];
    uint2 v[4];
    #pragma unroll
    for (int t = 0; t < 4; ++t) {
      dr[t] = dinv[r[t]];
      v[t] = *(const uint2*)(hw + (size_t)r[t] * 128 + j);
    }
    #pragma unroll
    for (int t = 0; t < 4; ++t) {
      float f[4];
      bf4_unpack(v[t], f);
      #pragma unroll
      for (int q = 0; q < 4; ++q) acc[q] = fmaf(dr[t], f[q], acc[q]);
    }
  }
  for (; e < end; ++e) {
    const int r0 = sorted_row[e];
    const float d0 = dinv[r0];
    const uint2 v0 = *(const uint2*)(hw + (size_t)r0 * 128 + j);
    float f[4];
    bf4_unpack(v0, f);
    #pragma unroll
    for (int q = 0; q < 4; ++q) acc[q] = fmaf(d0, f[q], acc[q]);
  }

  const float4 bb = *(const float4*)(bias + j);
  const float o0 = fmaxf(fmaf(dc, acc[0], bb.x), 0.f);
  const float o1 = fmaxf(fmaf(dc, acc[1], bb.y), 0.f);
  const float o2 = fmaxf(fmaf(dc, acc[2], bb.z), 0.f);
  const float o3 = fmaxf(fmaf(dc, acc[3], bb.w), 0.f);
  uint2 st;
  st.x = bfpack(o0, o1);
  st.y = bfpack(o2, o3);
  *(uint2*)(hcat + (size_t)g * 384 + koff + j) = st;
}

// ---- final: out = hcat(bf16) @ Wlin + blin, K=384, 12 chunks of 32 --------
__global__ __launch_bounds__(256, 2) void k_final(
    const unsigned short* __restrict__ hcat, const float* __restrict__ Wlin,
    const float* __restrict__ blin, float* __restrict__ out, int N) {
  __shared__ __align__(16) float hsT[32][128];
  __shared__ __align__(16) float Ws[32][64];
  const int tid = threadIdx.x;
  const int n0 = blockIdx.x * 128;
  const int rows = min(128, N - n0);
  const int tc = (tid & 15) << 2;
  const int tr = (tid >> 4) << 3;
  float acc[8][4] = {};
  uint4 pa[2];

  auto loadA = [&](int kc) {
    #pragma unroll
    for (int u = 0; u < 2; ++u) {
      const int i = tid + 256 * u;
      const int r = i >> 2, k8 = (i & 3) << 3;
      uint4 v = make_uint4(0u, 0u, 0u, 0u);
      if (r < rows) v = *(const uint4*)(hcat + (size_t)(n0 + r) * 384 + kc + k8);
      pa[u] = v;
    }
  };
  auto stageA = [&]() {
    #pragma unroll
    for (int u = 0; u < 2; ++u) {
      const int i = tid + 256 * u;
      const int r = i >> 2, k8 = (i & 3) << 3;
      float f[8];
      bf8_unpack(pa[u], f);
      #pragma unroll
      for (int t = 0; t < 4; ++t) {
        const int k = k8 + 2 * t;
        const int c = r ^ (k & 28);
        hsT[k][c] = f[2 * t];
        hsT[k + 1][c] = f[2 * t + 1];
      }
    }
  };
  auto stageW = [&](int kc) {
    #pragma unroll
    for (int u = 0; u < 2; ++u) {
      const int i = tid + 256 * u;
      const int k = i >> 4, c = (i & 15) << 2;
      *(float4*)&Ws[k][c] = *(const float4*)(Wlin + (size_t)(kc + k) * 64 + c);
    }
  };

  loadA(0);
  for (int kc = 0; kc < 384; kc += 32) {
    stageW(kc);
    stageA();
    __syncthreads();
    if (kc + 32 < 384) loadA(kc + 32);
    #pragma unroll
    for (int k = 0; k < 32; ++k) {
      const int s = k & 28;
      const float4 a0 = *(const float4*)&hsT[k][tr ^ s];
      const float4 a1 = *(const float4*)&hsT[k][(tr + 4) ^ s];
      const float4 w0 = *(const float4*)&Ws[k][tc];
      const float a[8] = {a0.x, a0.y, a0.z, a0.w, a1.x, a1.y, a1.z, a1.w};
      const float w[4] = {w0.x, w0.y, w0.z, w0.w};
      #pragma unroll
      for (int i = 0; i < 8; ++i)
        #pragma unroll
        for (int j = 0; j < 4; ++j) acc[i][j] = fmaf(a[i], w[j], acc[i][j]);
    }
    __syncthreads();
  }

  #pragma unroll
  for (int i = 0; i < 8; ++i) {
    const int r = tr + i;
    if (r < rows) {
      const float4 bb = *(const float4*)(blin + tc);
      *(float4*)(out + (size_t)(n0 + r) * 64 + tc) =
          make_float4(acc[i][0] + bb.x, acc[i][1] + bb.y,
                      acc[i][2] + bb.z, acc[i][3] + bb.w);
    }
  }
}

extern "C" void kernel_launch(void* const* d_in, const int* in_sizes, int n_in,
                              void* d_out, int out_size, void* d_ws, size_t ws_size,
                              hipStream_t stream) {
  const float* x    = (const float*)d_in[0];
  const int*   ei   = (const int*)d_in[1];
  const float* W1   = (const float*)d_in[2];
  const float* b1   = (const float*)d_in[3];
  const float* W2   = (const float*)d_in[4];
  const float* b2   = (const float*)d_in[5];
  const float* W3   = (const float*)d_in[6];
  const float* b3   = (const float*)d_in[7];
  const float* Wlin = (const float*)d_in[8];
  const float* blin = (const float*)d_in[9];

  const int N = in_sizes[0] / 128;
  const int E = in_sizes[1] / 2;
  const int* rowi = ei;
  const int* coli = ei + E;

  // ws: degi | dinv | offs | cursor | bsums | sorted_row | WT2 | WT3 | hw | hcat
  char* ws = (char*)d_ws;
  const size_t nb4 = (((size_t)N * 4) + 255) & ~(size_t)255;
  int*   degi       = (int*)ws;                 ws += nb4;
  float* dinv       = (float*)ws;               ws += nb4;
  int*   offs       = (int*)ws;                 ws += nb4;
  int*   cursor     = (int*)ws;                 ws += nb4;
  int*   bsums      = (int*)ws;                 ws += 1024;
  int*   sorted_row = (int*)ws;                 ws += (((size_t)E * 4) + 255) & ~(size_t)255;
  unsigned short* WT2  = (unsigned short*)ws;   ws += 128 * 128 * 2;
  unsigned short* WT3  = (unsigned short*)ws;   ws += 128 * 128 * 2;
  unsigned short* hw   = (unsigned short*)ws;   ws += (size_t)N * 128 * 2;
  unsigned short* hcat = (unsigned short*)ws;

  const int nblk = (N + 1023) / 1024;
  const int gemmBlocks = (N + 127) / 128;
  const int gb0 = gemmBlocks / 2;
  const int gb1 = gemmBlocks - gb0;
  const int degBlocks  = (E + 2047) / 2048;
  const int fillBlocks = (E + 1023) / 1024;
  const int aggBlocks  = (N + 7) / 8;

  k_wt<<<128, 256, 0, stream>>>(W2, W3, WT2, WT3);
  hipMemsetAsync(degi, 0, (size_t)N * 4, stream);
  k_mega0<<<gb0 + degBlocks, 256, 0, stream>>>(x, W1, hw, N, gb0, coli, E, degi);
  k_scan1<<<nblk, 256, 0, stream>>>(degi, N, offs, bsums, dinv);
  k_scan2<<<1, 128, 0, stream>>>(bsums, nblk);
  k_scan3<<<nblk, 256, 0, stream>>>(offs, bsums, cursor, N);
  k_mega1<<<gb1 + fillBlocks, 256, 0, stream>>>(x, W1, hw, N, gb1, gb0,
                                                rowi, coli, cursor, sorted_row, E);

  k_agg<<<aggBlocks, 256, 0, stream>>>(offs, degi, sorted_row, dinv, hw,
                                       b1, hcat, 0, N);
  k_gemm_mfma<<<gemmBlocks, 256, 0, stream>>>(hcat, 384, WT2, hw, N);
  k_agg<<<aggBlocks, 256, 0, stream>>>(offs, degi, sorted_row, dinv, hw,
                                       b2, hcat, 128, N);
  k_gemm_mfma<<<gemmBlocks, 256, 0, stream>>>(hcat + 128, 384, WT3, hw, N);
  k_agg<<<aggBlocks, 256, 0, stream>>>(offs, degi, sorted_row, dinv, hw,
                                       b3, hcat, 256, N);
  k_final<<<gemmBlocks, 256, 0, stream>>>(hcat, Wlin, blin, (float*)d_out, N);
}

// Round 14
// 473.828 us; speedup vs baseline: 1.2759x; 1.0460x over previous
//
#include <hip/hip_runtime.h>
#include <hip/hip_bf16.h>

// ---------------------------------------------------------------------------
// GCN via device-built CSR (no f32 atomics), all inter-kernel tensors bf16.
// r13 + MFMA final + mega rebalance (1/3 gemm1 in mega0, 2/3 in mega1):
//   k_wt: W2,W3 -> WT bf16 [n][k]; Wlin -> WTL bf16 [n][k=384]
//   mega0=[gemm1 1/3 | deg]  scan  mega1=[gemm1 2/3 | CSR fill]
//   3x [ hw = bf16(hprev @ W) via mfma (layers 2,3) ; agg -> hcat bf16 ]
//   out = hcat @ Wlin + blin via mfma (3 K-chunks of 128)
// MFMA kernels: mfma_f32_32x32x16_bf16, LDS XOR swizzle byte^=(row&7)<<4,
// C/D map col=lane&31, row=(q&3)+8*(q>>2)+4*(lane>>5) [verified r13].
// ---------------------------------------------------------------------------

typedef __attribute__((ext_vector_type(8))) short bf16x8;
typedef __attribute__((ext_vector_type(16))) float f32x16;

__device__ __forceinline__ unsigned short f2bf(float f) {  // RNE f32->bf16
  unsigned int u = __float_as_uint(f);
  u += 0x7FFFu + ((u >> 16) & 1u);
  return (unsigned short)(u >> 16);
}
__device__ __forceinline__ unsigned int bfpack(float a, float b) {
  return ((unsigned int)f2bf(a)) | ((unsigned int)f2bf(b) << 16);
}
__device__ __forceinline__ void bf4_unpack(uint2 v, float* f) {
  f[0] = __uint_as_float(v.x << 16); f[1] = __uint_as_float(v.x & 0xFFFF0000u);
  f[2] = __uint_as_float(v.y << 16); f[3] = __uint_as_float(v.y & 0xFFFF0000u);
}

// ---- weight transposes: W2,W3 -> WT[128][128]; Wlin -> WTL[64][384] -------
__global__ __launch_bounds__(256) void k_wt(
    const float* __restrict__ W2, const float* __restrict__ W3,
    const float* __restrict__ Wlin,
    unsigned short* __restrict__ WT2, unsigned short* __restrict__ WT3,
    unsigned short* __restrict__ WTL) {
  const int idx = blockIdx.x * 256 + threadIdx.x;  // 32768 + 24576 total
  if (idx < 32768) {
    const int w = idx >> 14;
    const int rem = idx & 16383;
    const int n = rem >> 7, k = rem & 127;
    const float* W = w ? W3 : W2;
    unsigned short* WT = w ? WT3 : WT2;
    WT[n * 128 + k] = f2bf(W[k * 128 + n]);
  } else if (idx < 32768 + 24576) {
    const int rem = idx - 32768;
    const int n = rem / 384, k = rem - n * 384;
    WTL[n * 384 + k] = f2bf(Wlin[k * 64 + n]);
  }
}

// ---- GEMM body, f32 A (layer 1: A = x) -> hw bf16 -------------------------
__device__ __forceinline__ void gemm128_f32(
    const float* __restrict__ A, long long lda,
    const float* __restrict__ W, unsigned short* __restrict__ hw, int N, int n0,
    float (*hsT)[128], float (*Ws)[128]) {
  const int tid = threadIdx.x;
  const int rows = min(128, N - n0);
  const int tc4 = (tid & 15) << 2;
  const int tr = (tid >> 4) << 3;
  float acc[8][8] = {};
  float4 pa[4];

  auto loadA = [&](int kc) {
    #pragma unroll
    for (int u = 0; u < 4; ++u) {
      const int i = tid + 256 * u;
      const int r = i >> 3, k4 = (i & 7) << 2;
      float4 v = make_float4(0.f, 0.f, 0.f, 0.f);
      if (r < rows) v = *(const float4*)(A + (size_t)(n0 + r) * lda + kc + k4);
      pa[u] = v;
    }
  };
  auto stageA = [&]() {
    #pragma unroll
    for (int u = 0; u < 4; ++u) {
      const int i = tid + 256 * u;
      const int r = i >> 3, k4 = (i & 7) << 2;
      const int c = r ^ k4;
      hsT[k4 + 0][c] = pa[u].x; hsT[k4 + 1][c] = pa[u].y;
      hsT[k4 + 2][c] = pa[u].z; hsT[k4 + 3][c] = pa[u].w;
    }
  };
  auto stageW = [&](int kc) {
    #pragma unroll
    for (int u = 0; u < 4; ++u) {
      const int i = tid + 256 * u;
      const int k = i >> 5, c = (i & 31) << 2;
      *(float4*)&Ws[k][c] = *(const float4*)(W + (size_t)(kc + k) * 128 + c);
    }
  };

  loadA(0);
  for (int kc = 0; kc < 128; kc += 32) {
    stageW(kc);
    stageA();
    __syncthreads();
    if (kc + 32 < 128) loadA(kc + 32);
    #pragma unroll
    for (int k = 0; k < 32; ++k) {
      const int s = k & 28;
      const float4 a0 = *(const float4*)&hsT[k][tr ^ s];
      const float4 a1 = *(const float4*)&hsT[k][(tr + 4) ^ s];
      const float4 w0 = *(const float4*)&Ws[k][tc4];
      const float4 w1 = *(const float4*)&Ws[k][tc4 + 64];
      const float a[8] = {a0.x, a0.y, a0.z, a0.w, a1.x, a1.y, a1.z, a1.w};
      const float w[8] = {w0.x, w0.y, w0.z, w0.w, w1.x, w1.y, w1.z, w1.w};
      #pragma unroll
      for (int i = 0; i < 8; ++i)
        #pragma unroll
        for (int j = 0; j < 8; ++j) acc[i][j] = fmaf(a[i], w[j], acc[i][j]);
    }
    __syncthreads();
  }

  #pragma unroll
  for (int i = 0; i < 8; ++i) {
    const int r = tr + i;
    if (r < rows) {
      unsigned short* hwp = hw + (size_t)(n0 + r) * 128;
      ushort4 o0, o1;
      o0.x = f2bf(acc[i][0]); o0.y = f2bf(acc[i][1]);
      o0.z = f2bf(acc[i][2]); o0.w = f2bf(acc[i][3]);
      o1.x = f2bf(acc[i][4]); o1.y = f2bf(acc[i][5]);
      o1.z = f2bf(acc[i][6]); o1.w = f2bf(acc[i][7]);
      *(ushort4*)(hwp + tc4) = o0;
      *(ushort4*)(hwp + tc4 + 64) = o1;
    }
  }
}

// ---- MFMA GEMM (layers 2,3): hw = bf16(A_bf16 @ W) via WT -----------------
__global__ __launch_bounds__(256, 2) void k_gemm_mfma(
    const unsigned short* __restrict__ A, long long lda,
    const unsigned short* __restrict__ WT, unsigned short* __restrict__ hw,
    int N) {
  __shared__ __align__(16) unsigned short hs[128 * 128];
  __shared__ __align__(16) unsigned short WsT[128 * 128];
  const int tid = threadIdx.x;
  const int n0 = blockIdx.x * 128;
  const int rows = min(128, N - n0);
  char* hsb = (char*)hs;
  char* wsb = (char*)WsT;

  #pragma unroll
  for (int u = 0; u < 8; ++u) {
    const int i = tid + 256 * u;
    const int r = i >> 4, k8 = (i & 15) << 3;
    uint4 v = make_uint4(0u, 0u, 0u, 0u);
    if (r < rows) v = *(const uint4*)(A + (size_t)(n0 + r) * lda + k8);
    *(uint4*)(hsb + ((r * 256 + k8 * 2) ^ ((r & 7) << 4))) = v;
  }
  #pragma unroll
  for (int u = 0; u < 8; ++u) {
    const int i = tid + 256 * u;
    const int nn = i >> 4, k8 = (i & 15) << 3;
    const uint4 v = *(const uint4*)(WT + nn * 128 + k8);
    *(uint4*)(wsb + ((nn * 256 + k8 * 2) ^ ((nn & 7) << 4))) = v;
  }
  __syncthreads();

  const int l = tid & 63;
  const int m0 = (tid >> 6) << 5;
  const int lm = l & 31;
  const int lk = (l >> 5) << 3;
  const int ra = m0 + lm;
  f32x16 acc[4];
  #pragma unroll
  for (int t = 0; t < 4; ++t)
    #pragma unroll
    for (int q = 0; q < 16; ++q) acc[t][q] = 0.f;

  #pragma unroll
  for (int ks = 0; ks < 8; ++ks) {
    const int kb = (ks * 16 + lk) * 2;
    const bf16x8 af = *(const bf16x8*)(hsb + ((ra * 256 + kb) ^ ((ra & 7) << 4)));
    #pragma unroll
    for (int t = 0; t < 4; ++t) {
      const int rb = t * 32 + lm;
      const bf16x8 bfr = *(const bf16x8*)(wsb + ((rb * 256 + kb) ^ ((rb & 7) << 4)));
      acc[t] = __builtin_amdgcn_mfma_f32_32x32x16_bf16(af, bfr, acc[t], 0, 0, 0);
    }
  }

  #pragma unroll
  for (int t = 0; t < 4; ++t) {
    #pragma unroll
    for (int q = 0; q < 16; ++q) {
      const int m = m0 + (q & 3) + ((q >> 2) << 3) + ((l >> 5) << 2);
      if (m < rows) hw[(size_t)(n0 + m) * 128 + t * 32 + lm] = f2bf(acc[t][q]);
    }
  }
}

// ---- MFMA final: out = hcat(bf16) @ Wlin + blin, 3 K-chunks of 128 --------
__global__ __launch_bounds__(256, 2) void k_final_mfma(
    const unsigned short* __restrict__ hcat, const unsigned short* __restrict__ WTL,
    const float* __restrict__ blin, float* __restrict__ out, int N) {
  __shared__ __align__(16) unsigned short hs[128 * 128];  // 32KB
  __shared__ __align__(16) unsigned short WsT[64 * 128];  // 16KB
  const int tid = threadIdx.x;
  const int n0 = blockIdx.x * 128;
  const int rows = min(128, N - n0);
  char* hsb = (char*)hs;
  char* wsb = (char*)WsT;

  const int l = tid & 63;
  const int m0 = (tid >> 6) << 5;
  const int lm = l & 31;
  const int lk = (l >> 5) << 3;
  const int ra = m0 + lm;
  f32x16 acc[2];
  #pragma unroll
  for (int t = 0; t < 2; ++t)
    #pragma unroll
    for (int q = 0; q < 16; ++q) acc[t][q] = 0.f;

  for (int kc = 0; kc < 384; kc += 128) {
    // stage A chunk: 128 rows x 128 K (swizzled)
    #pragma unroll
    for (int u = 0; u < 8; ++u) {
      const int i = tid + 256 * u;
      const int r = i >> 4, k8 = (i & 15) << 3;
      uint4 v = make_uint4(0u, 0u, 0u, 0u);
      if (r < rows) v = *(const uint4*)(hcat + (size_t)(n0 + r) * 384 + kc + k8);
      *(uint4*)(hsb + ((r * 256 + k8 * 2) ^ ((r & 7) << 4))) = v;
    }
    // stage WTL chunk: 64 n-rows x 128 K (swizzled)
    #pragma unroll
    for (int u = 0; u < 4; ++u) {
      const int i = tid + 256 * u;
      const int nn = i >> 4, k8 = (i & 15) << 3;
      const uint4 v = *(const uint4*)(WTL + nn * 384 + kc + k8);
      *(uint4*)(wsb + ((nn * 256 + k8 * 2) ^ ((nn & 7) << 4))) = v;
    }
    __syncthreads();

    #pragma unroll
    for (int ks = 0; ks < 8; ++ks) {
      const int kb = (ks * 16 + lk) * 2;
      const bf16x8 af = *(const bf16x8*)(hsb + ((ra * 256 + kb) ^ ((ra & 7) << 4)));
      #pragma unroll
      for (int t = 0; t < 2; ++t) {
        const int rb = t * 32 + lm;
        const bf16x8 bfr = *(const bf16x8*)(wsb + ((rb * 256 + kb) ^ ((rb & 7) << 4)));
        acc[t] = __builtin_amdgcn_mfma_f32_32x32x16_bf16(af, bfr, acc[t], 0, 0, 0);
      }
    }
    __syncthreads();
  }

  #pragma unroll
  for (int t = 0; t < 2; ++t) {
    const float bb = blin[t * 32 + lm];
    #pragma unroll
    for (int q = 0; q < 16; ++q) {
      const int m = m0 + (q & 3) + ((q >> 2) << 3) + ((l >> 5) << 2);
      if (m < rows) out[(size_t)(n0 + m) * 64 + t * 32 + lm] = acc[t][q] + bb;
    }
  }
}

// ---- mega0: [gemm1 first third | degree count] (gemm blocks first) --------
__global__ __launch_bounds__(256, 2) void k_mega0(
    const float* __restrict__ x, const float* __restrict__ W1,
    unsigned short* __restrict__ hw, int N, int gb,
    const int* __restrict__ coli, int E, int* __restrict__ degi) {
  __shared__ __align__(16) float hsT[32][128];
  __shared__ __align__(16) float Ws[32][128];
  if ((int)blockIdx.x < gb) {
    gemm128_f32(x, 128, W1, hw, N, blockIdx.x * 128, hsT, Ws);
  } else {
    const int b = blockIdx.x - gb;
    #pragma unroll
    for (int h = 0; h < 2; ++h) {
      const int base = b * 2048 + h * 1024 + (int)threadIdx.x * 4;
      if (base + 3 < E) {
        const int4 c4 = *(const int4*)(coli + base);
        atomicAdd(&degi[c4.x], 1); atomicAdd(&degi[c4.y], 1);
        atomicAdd(&degi[c4.z], 1); atomicAdd(&degi[c4.w], 1);
      } else {
        for (int e = base; e < E; ++e) atomicAdd(&degi[coli[e]], 1);
      }
    }
  }
}

// ---- mega1: [gemm1 rest | CSR fill] (gemm blocks first) -------------------
__global__ __launch_bounds__(256, 2) void k_mega1(
    const float* __restrict__ x, const float* __restrict__ W1,
    unsigned short* __restrict__ hw, int N, int gb, int goff,
    const int* __restrict__ rowi, const int* __restrict__ coli,
    int* __restrict__ cursor, int* __restrict__ sorted_row, int E) {
  __shared__ __align__(16) float hsT[32][128];
  __shared__ __align__(16) float Ws[32][128];
  if ((int)blockIdx.x < gb) {
    gemm128_f32(x, 128, W1, hw, N, (goff + blockIdx.x) * 128, hsT, Ws);
  } else {
    const int b = blockIdx.x - gb;
    const int base = b * 1024 + (int)threadIdx.x * 4;
    if (base + 3 < E) {
      const int4 c4 = *(const int4*)(coli + base);
      const int4 r4 = *(const int4*)(rowi + base);
      int p;
      p = atomicAdd(&cursor[c4.x], 1); __builtin_nontemporal_store(r4.x, &sorted_row[p]);
      p = atomicAdd(&cursor[c4.y], 1); __builtin_nontemporal_store(r4.y, &sorted_row[p]);
      p = atomicAdd(&cursor[c4.z], 1); __builtin_nontemporal_store(r4.z, &sorted_row[p]);
      p = atomicAdd(&cursor[c4.w], 1); __builtin_nontemporal_store(r4.w, &sorted_row[p]);
    } else {
      for (int e = base; e < E; ++e) {
        const int p = atomicAdd(&cursor[coli[e]], 1);
        __builtin_nontemporal_store(rowi[e], &sorted_row[p]);
      }
    }
  }
}

// ---- scan passes ----------------------------------------------------------
__global__ __launch_bounds__(256) void k_scan1(const int* __restrict__ degi, int N,
                                               int* __restrict__ offs,
                                               int* __restrict__ bsums,
                                               float* __restrict__ dinv) {
  __shared__ int sm[256];
  const int b = blockIdx.x, t = threadIdx.x;
  const int base = b * 1024 + t * 4;
  int v[4];
  #pragma unroll
  for (int i = 0; i < 4; ++i) v[i] = (base + i < N) ? degi[base + i] : 0;
  #pragma unroll
  for (int i = 0; i < 4; ++i)
    if (base + i < N) dinv[base + i] = rsqrtf(1.0f + (float)v[i]);
  const int s = v[0] + v[1] + v[2] + v[3];
  sm[t] = s;
  __syncthreads();
  for (int ofs = 1; ofs < 256; ofs <<= 1) {
    const int add = (t >= ofs) ? sm[t - ofs] : 0;
    __syncthreads();
    sm[t] += add;
    __syncthreads();
  }
  if (t == 255) bsums[b] = sm[255];
  int run = sm[t] - s;
  #pragma unroll
  for (int i = 0; i < 4; ++i) {
    if (base + i < N) offs[base + i] = run;
    run += v[i];
  }
}

__global__ __launch_bounds__(128) void k_scan2(int* __restrict__ bsums, int nb) {
  __shared__ int sm[128];
  const int t = threadIdx.x;
  const int v = (t < nb) ? bsums[t] : 0;
  sm[t] = v;
  __syncthreads();
  for (int ofs = 1; ofs < 128; ofs <<= 1) {
    const int add = (t >= ofs) ? sm[t - ofs] : 0;
    __syncthreads();
    sm[t] += add;
    __syncthreads();
  }
  if (t < nb) bsums[t] = sm[t] - v;
}

__global__ __launch_bounds__(256) void k_scan3(int* __restrict__ offs,
                                               const int* __restrict__ bsums,
                                               int* __restrict__ cursor, int N) {
  const int add = bsums[blockIdx.x];
  const int base = blockIdx.x * 1024 + threadIdx.x * 4;
  #pragma unroll
  for (int i = 0; i < 4; ++i) {
    const int idx = base + i;
    if (idx < N) {
      const int o = offs[idx] + add;
      offs[idx] = o;
      cursor[idx] = o;
    }
  }
}

// ---- segment aggregate (32 lanes/node, ushort4/lane, 8-deep gather) -------
__global__ __launch_bounds__(256) void k_agg(
    const int* __restrict__ offs, const int* __restrict__ degi,
    const int* __restrict__ sorted_row, const float* __restrict__ dinv,
    const unsigned short* __restrict__ hw, const float* __restrict__ bias,
    unsigned short* __restrict__ hcat, int koff, int N) {
  const int g = (int)((blockIdx.x * 256 + threadIdx.x) >> 5);
  if (g >= N) return;
  const int j = (threadIdx.x & 31) << 2;
  const float dc = dinv[g];
  float acc[4];
  {
    const uint2 sv = *(const uint2*)(hw + (size_t)g * 128 + j);
    float f[4];
    bf4_unpack(sv, f);
    #pragma unroll
    for (int q = 0; q < 4; ++q) acc[q] = dc * f[q];
  }

  const int off = offs[g];
  const int end = off + degi[g];
  int e = off;
  for (; e + 7 < end; e += 8) {
    int r[8];
    #pragma unroll
    for (int t = 0; t < 8; ++t) r[t] = sorted_row[e + t];
    float dr[8];
    uint2 v[8];
    #pragma unroll
    for (int t = 0; t < 8; ++t) {
      dr[t] = dinv[r[t]];
      v[t] = *(const uint2*)(hw + (size_t)r[t] * 128 + j);
    }
    #pragma unroll
    for (int t = 0; t < 8; ++t) {
      float f[4];
      bf4_unpack(v[t], f);
      #pragma unroll
      for (int q = 0; q < 4; ++q) acc[q] = fmaf(dr[t], f[q], acc[q]);
    }
  }
  for (; e + 3 < end; e += 4) {
    int r[4];
    #pragma unroll
    for (int t = 0; t < 4; ++t) r[t] = sorted_row[e + t];
    float dr[4];
    uint2 v[4];
    #pragma unroll
    for (int t = 0; t < 4; ++t) {
      dr[t] = dinv[r[t]];
      v[t] = *(const uint2*)(hw + (size_t)r[t] * 128 + j);
    }
    #pragma unroll
    for (int t = 0; t < 4; ++t) {
      float f[4];
      bf4_unpack(v[t], f);
      #pragma unroll
      for (int q = 0; q < 4; ++q) acc[q] = fmaf(dr[t], f[q], acc[q]);
    }
  }
  for (; e < end; ++e) {
    const int r0 = sorted_row[e];
    const float d0 = dinv[r0];
    const uint2 v0 = *(const uint2*)(hw + (size_t)r0 * 128 + j);
    float f[4];
    bf4_unpack(v0, f);
    #pragma unroll
    for (int q = 0; q < 4; ++q) acc[q] = fmaf(d0, f[q], acc[q]);
  }

  const float4 bb = *(const float4*)(bias + j);
  const float o0 = fmaxf(fmaf(dc, acc[0], bb.x), 0.f);
  const float o1 = fmaxf(fmaf(dc, acc[1], bb.y), 0.f);
  const float o2 = fmaxf(fmaf(dc, acc[2], bb.z), 0.f);
  const float o3 = fmaxf(fmaf(dc, acc[3], bb.w), 0.f);
  uint2 st;
  st.x = bfpack(o0, o1);
  st.y = bfpack(o2, o3);
  *(uint2*)(hcat + (size_t)g * 384 + koff + j) = st;
}

extern "C" void kernel_launch(void* const* d_in, const int* in_sizes, int n_in,
                              void* d_out, int out_size, void* d_ws, size_t ws_size,
                              hipStream_t stream) {
  const float* x    = (const float*)d_in[0];
  const int*   ei   = (const int*)d_in[1];
  const float* W1   = (const float*)d_in[2];
  const float* b1   = (const float*)d_in[3];
  const float* W2   = (const float*)d_in[4];
  const float* b2   = (const float*)d_in[5];
  const float* W3   = (const float*)d_in[6];
  const float* b3   = (const float*)d_in[7];
  const float* Wlin = (const float*)d_in[8];
  const float* blin = (const float*)d_in[9];

  const int N = in_sizes[0] / 128;
  const int E = in_sizes[1] / 2;
  const int* rowi = ei;
  const int* coli = ei + E;

  // ws: degi|dinv|offs|cursor|bsums|sorted_row|WT2|WT3|WTL|hw|hcat
  char* ws = (char*)d_ws;
  const size_t nb4 = (((size_t)N * 4) + 255) & ~(size_t)255;
  int*   degi       = (int*)ws;                 ws += nb4;
  float* dinv       = (float*)ws;               ws += nb4;
  int*   offs       = (int*)ws;                 ws += nb4;
  int*   cursor     = (int*)ws;                 ws += nb4;
  int*   bsums      = (int*)ws;                 ws += 1024;
  int*   sorted_row = (int*)ws;                 ws += (((size_t)E * 4) + 255) & ~(size_t)255;
  unsigned short* WT2  = (unsigned short*)ws;   ws += 128 * 128 * 2;
  unsigned short* WT3  = (unsigned short*)ws;   ws += 128 * 128 * 2;
  unsigned short* WTL  = (unsigned short*)ws;   ws += 64 * 384 * 2;
  unsigned short* hw   = (unsigned short*)ws;   ws += (size_t)N * 128 * 2;
  unsigned short* hcat = (unsigned short*)ws;

  const int nblk = (N + 1023) / 1024;
  const int gemmBlocks = (N + 127) / 128;
  const int gb0 = gemmBlocks / 3;          // gemm1 share in mega0 (covers deg)
  const int gb1 = gemmBlocks - gb0;        // gemm1 share in mega1 (fill shadow)
  const int degBlocks  = (E + 2047) / 2048;
  const int fillBlocks = (E + 1023) / 1024;
  const int aggBlocks  = (N + 7) / 8;

  k_wt<<<(32768 + 24576 + 255) / 256, 256, 0, stream>>>(W2, W3, Wlin, WT2, WT3, WTL);
  hipMemsetAsync(degi, 0, (size_t)N * 4, stream);
  k_mega0<<<gb0 + degBlocks, 256, 0, stream>>>(x, W1, hw, N, gb0, coli, E, degi);
  k_scan1<<<nblk, 256, 0, stream>>>(degi, N, offs, bsums, dinv);
  k_scan2<<<1, 128, 0, stream>>>(bsums, nblk);
  k_scan3<<<nblk, 256, 0, stream>>>(offs, bsums, cursor, N);
  k_mega1<<<gb1 + fillBlocks, 256, 0, stream>>>(x, W1, hw, N, gb1, gb0,
                                                rowi, coli, cursor, sorted_row, E);

  k_agg<<<aggBlocks, 256, 0, stream>>>(offs, degi, sorted_row, dinv, hw,
                                       b1, hcat, 0, N);
  k_gemm_mfma<<<gemmBlocks, 256, 0, stream>>>(hcat, 384, WT2, hw, N);
  k_agg<<<aggBlocks, 256, 0, stream>>>(offs, degi, sorted_row, dinv, hw,
                                       b2, hcat, 128, N);
  k_gemm_mfma<<<gemmBlocks, 256, 0, stream>>>(hcat + 128, 384, WT3, hw, N);
  k_agg<<<aggBlocks, 256, 0, stream>>>(offs, degi, sorted_row, dinv, hw,
                                       b3, hcat, 256, N);
  k_final_mfma<<<gemmBlocks, 256, 0, stream>>>(hcat, WTL, blin, (float*)d_out, N);
}

// Round 15
// 472.146 us; speedup vs baseline: 1.2805x; 1.0036x over previous
//
#include <hip/hip_runtime.h>
#include <hip/hip_bf16.h>

// ---------------------------------------------------------------------------
// GCN via device-built CSR (no f32 atomics), all tensors bf16, all GEMMs MFMA:
//   k_wt: W1,W2,W3 -> WT bf16 [n][k]; Wlin -> WTL bf16 [n][384]
//   mega0 = [x->bf16 conv | deg count]        (no LDS, high occupancy)
//   scans ; mega1 = [gemm1 MFMA (BK=64, 32KB LDS) | CSR fill]
//     (32KB keeps fill at 5 blocks/CU; 64KB full-K would halve fill occupancy)
//   3x [ agg -> hcat bf16 ; gemm_{k+1} MFMA ] ; final MFMA
// MFMA: mfma_f32_32x32x16_bf16, LDS XOR swizzle byte^=(row&7)<<4 (4-way ~free),
// C/D map col=lane&31, row=(q&3)+8*(q>>2)+4*(lane>>5) [verified r13/r14].
// Mega lesson (r14): a mega-kernel hides only min(short-side, long-side-slack);
// gemm1 made tiny via MFMA so it fully vanishes under fill's ~105us floor.
// ---------------------------------------------------------------------------

typedef __attribute__((ext_vector_type(8))) short bf16x8;
typedef __attribute__((ext_vector_type(16))) float f32x16;

__device__ __forceinline__ unsigned short f2bf(float f) {  // RNE f32->bf16
  unsigned int u = __float_as_uint(f);
  u += 0x7FFFu + ((u >> 16) & 1u);
  return (unsigned short)(u >> 16);
}
__device__ __forceinline__ unsigned int bfpack(float a, float b) {
  return ((unsigned int)f2bf(a)) | ((unsigned int)f2bf(b) << 16);
}
__device__ __forceinline__ void bf4_unpack(uint2 v, float* f) {
  f[0] = __uint_as_float(v.x << 16); f[1] = __uint_as_float(v.x & 0xFFFF0000u);
  f[2] = __uint_as_float(v.y << 16); f[3] = __uint_as_float(v.y & 0xFFFF0000u);
}

// ---- weight transposes: W1..W3 -> WT[128][128]; Wlin -> WTL[64][384] ------
__global__ __launch_bounds__(256) void k_wt(
    const float* __restrict__ W1, const float* __restrict__ W2,
    const float* __restrict__ W3, const float* __restrict__ Wlin,
    unsigned short* __restrict__ WT1, unsigned short* __restrict__ WT2,
    unsigned short* __restrict__ WT3, unsigned short* __restrict__ WTL) {
  const int idx = blockIdx.x * 256 + threadIdx.x;  // 49152 + 24576
  if (idx < 49152) {
    const int w = idx >> 14;
    const int rem = idx & 16383;
    const int n = rem >> 7, k = rem & 127;
    const float* W = (w == 0) ? W1 : (w == 1) ? W2 : W3;
    unsigned short* WT = (w == 0) ? WT1 : (w == 1) ? WT2 : WT3;
    WT[n * 128 + k] = f2bf(W[k * 128 + n]);
  } else if (idx < 49152 + 24576) {
    const int rem = idx - 49152;
    const int n = rem / 384, k = rem - n * 384;
    WTL[n * 384 + k] = f2bf(Wlin[k * 64 + n]);
  }
}

// ---- mega0: [x->bf16 conversion | degree count] (no LDS) ------------------
__global__ __launch_bounds__(256) void k_mega0(
    const float* __restrict__ x, unsigned short* __restrict__ xb, int N, int cb,
    const int* __restrict__ coli, int E, int* __restrict__ degi) {
  if ((int)blockIdx.x < cb) {
    const long long idx = ((long long)blockIdx.x * 256 + threadIdx.x) * 8;
    if (idx + 7 < (long long)N * 128) {
      const float4 a = *(const float4*)(x + idx);
      const float4 b = *(const float4*)(x + idx + 4);
      uint4 o;
      o.x = bfpack(a.x, a.y); o.y = bfpack(a.z, a.w);
      o.z = bfpack(b.x, b.y); o.w = bfpack(b.z, b.w);
      *(uint4*)(xb + idx) = o;
    }
  } else {
    const int b = blockIdx.x - cb;
    #pragma unroll
    for (int h = 0; h < 2; ++h) {
      const int base = b * 2048 + h * 1024 + (int)threadIdx.x * 4;
      if (base + 3 < E) {
        const int4 c4 = *(const int4*)(coli + base);
        atomicAdd(&degi[c4.x], 1); atomicAdd(&degi[c4.y], 1);
        atomicAdd(&degi[c4.z], 1); atomicAdd(&degi[c4.w], 1);
      } else {
        for (int e = base; e < E; ++e) atomicAdd(&degi[coli[e]], 1);
      }
    }
  }
}

// ---- MFMA GEMM body, BK=64 chunks (32KB LDS total) ------------------------
__device__ __forceinline__ void gemm_mfma_bk64_body(
    const unsigned short* __restrict__ A, long long lda,
    const unsigned short* __restrict__ WT, unsigned short* __restrict__ hw,
    int N, int n0, char* hsb, char* wsb) {
  const int tid = threadIdx.x;
  const int rows = min(128, N - n0);
  const int l = tid & 63;
  const int m0 = (tid >> 6) << 5;
  const int lm = l & 31;
  const int lkb = (l >> 5) << 4;       // K byte sub-offset: 0 or 16
  const int ra = m0 + lm;
  f32x16 acc[4];
  #pragma unroll
  for (int t = 0; t < 4; ++t)
    #pragma unroll
    for (int q = 0; q < 16; ++q) acc[t][q] = 0.f;

  for (int kc = 0; kc < 128; kc += 64) {
    #pragma unroll
    for (int u = 0; u < 4; ++u) {     // stage A chunk: 128 rows x 64 K
      const int i = tid + 256 * u;
      const int r = i >> 3, k8 = (i & 7) << 3;
      uint4 v = make_uint4(0u, 0u, 0u, 0u);
      if (r < rows) v = *(const uint4*)(A + (size_t)(n0 + r) * lda + kc + k8);
      *(uint4*)(hsb + ((r * 128 + k8 * 2) ^ ((r & 7) << 4))) = v;
    }
    #pragma unroll
    for (int u = 0; u < 4; ++u) {     // stage WT chunk: 128 n x 64 K
      const int i = tid + 256 * u;
      const int nn = i >> 3, k8 = (i & 7) << 3;
      const uint4 v = *(const uint4*)(WT + nn * 128 + kc + k8);
      *(uint4*)(wsb + ((nn * 128 + k8 * 2) ^ ((nn & 7) << 4))) = v;
    }
    __syncthreads();
    #pragma unroll
    for (int ks = 0; ks < 4; ++ks) {
      const int kb = ks * 32 + lkb;
      const bf16x8 af = *(const bf16x8*)(hsb + ((ra * 128 + kb) ^ ((ra & 7) << 4)));
      #pragma unroll
      for (int t = 0; t < 4; ++t) {
        const int rb = t * 32 + lm;
        const bf16x8 bfr = *(const bf16x8*)(wsb + ((rb * 128 + kb) ^ ((rb & 7) << 4)));
        acc[t] = __builtin_amdgcn_mfma_f32_32x32x16_bf16(af, bfr, acc[t], 0, 0, 0);
      }
    }
    __syncthreads();
  }

  #pragma unroll
  for (int t = 0; t < 4; ++t) {
    #pragma unroll
    for (int q = 0; q < 16; ++q) {
      const int m = m0 + (q & 3) + ((q >> 2) << 3) + ((l >> 5) << 2);
      if (m < rows) hw[(size_t)(n0 + m) * 128 + t * 32 + lm] = f2bf(acc[t][q]);
    }
  }
}

// ---- mega1: [gemm1 MFMA (blocks first) | CSR fill] ------------------------
__global__ __launch_bounds__(256, 2) void k_mega1(
    const unsigned short* __restrict__ xb, const unsigned short* __restrict__ WT1,
    unsigned short* __restrict__ hw, int N, int gb,
    const int* __restrict__ rowi, const int* __restrict__ coli,
    int* __restrict__ cursor, int* __restrict__ sorted_row, int E) {
  __shared__ __align__(16) unsigned short hs[128 * 64];   // 16KB
  __shared__ __align__(16) unsigned short wsm[128 * 64];  // 16KB
  if ((int)blockIdx.x < gb) {
    gemm_mfma_bk64_body(xb, 128, WT1, hw, N, blockIdx.x * 128,
                        (char*)hs, (char*)wsm);
  } else {
    const int b = blockIdx.x - gb;
    const int base = b * 1024 + (int)threadIdx.x * 4;
    if (base + 3 < E) {
      const int4 c4 = *(const int4*)(coli + base);
      const int4 r4 = *(const int4*)(rowi + base);
      int p;
      p = atomicAdd(&cursor[c4.x], 1); __builtin_nontemporal_store(r4.x, &sorted_row[p]);
      p = atomicAdd(&cursor[c4.y], 1); __builtin_nontemporal_store(r4.y, &sorted_row[p]);
      p = atomicAdd(&cursor[c4.z], 1); __builtin_nontemporal_store(r4.z, &sorted_row[p]);
      p = atomicAdd(&cursor[c4.w], 1); __builtin_nontemporal_store(r4.w, &sorted_row[p]);
    } else {
      for (int e = base; e < E; ++e) {
        const int p = atomicAdd(&cursor[coli[e]], 1);
        __builtin_nontemporal_store(rowi[e], &sorted_row[p]);
      }
    }
  }
}

// ---- scan passes ----------------------------------------------------------
__global__ __launch_bounds__(256) void k_scan1(const int* __restrict__ degi, int N,
                                               int* __restrict__ offs,
                                               int* __restrict__ bsums,
                                               float* __restrict__ dinv) {
  __shared__ int sm[256];
  const int b = blockIdx.x, t = threadIdx.x;
  const int base = b * 1024 + t * 4;
  int v[4];
  #pragma unroll
  for (int i = 0; i < 4; ++i) v[i] = (base + i < N) ? degi[base + i] : 0;
  #pragma unroll
  for (int i = 0; i < 4; ++i)
    if (base + i < N) dinv[base + i] = rsqrtf(1.0f + (float)v[i]);
  const int s = v[0] + v[1] + v[2] + v[3];
  sm[t] = s;
  __syncthreads();
  for (int ofs = 1; ofs < 256; ofs <<= 1) {
    const int add = (t >= ofs) ? sm[t - ofs] : 0;
    __syncthreads();
    sm[t] += add;
    __syncthreads();
  }
  if (t == 255) bsums[b] = sm[255];
  int run = sm[t] - s;
  #pragma unroll
  for (int i = 0; i < 4; ++i) {
    if (base + i < N) offs[base + i] = run;
    run += v[i];
  }
}

__global__ __launch_bounds__(128) void k_scan2(int* __restrict__ bsums, int nb) {
  __shared__ int sm[128];
  const int t = threadIdx.x;
  const int v = (t < nb) ? bsums[t] : 0;
  sm[t] = v;
  __syncthreads();
  for (int ofs = 1; ofs < 128; ofs <<= 1) {
    const int add = (t >= ofs) ? sm[t - ofs] : 0;
    __syncthreads();
    sm[t] += add;
    __syncthreads();
  }
  if (t < nb) bsums[t] = sm[t] - v;
}

__global__ __launch_bounds__(256) void k_scan3(int* __restrict__ offs,
                                               const int* __restrict__ bsums,
                                               int* __restrict__ cursor, int N) {
  const int add = bsums[blockIdx.x];
  const int base = blockIdx.x * 1024 + threadIdx.x * 4;
  #pragma unroll
  for (int i = 0; i < 4; ++i) {
    const int idx = base + i;
    if (idx < N) {
      const int o = offs[idx] + add;
      offs[idx] = o;
      cursor[idx] = o;
    }
  }
}

// ---- MFMA GEMM (layers 2,3): full-K 64KB LDS (proven r13) -----------------
__global__ __launch_bounds__(256, 2) void k_gemm_mfma(
    const unsigned short* __restrict__ A, long long lda,
    const unsigned short* __restrict__ WT, unsigned short* __restrict__ hw,
    int N) {
  __shared__ __align__(16) unsigned short hs[128 * 128];
  __shared__ __align__(16) unsigned short WsT[128 * 128];
  const int tid = threadIdx.x;
  const int n0 = blockIdx.x * 128;
  const int rows = min(128, N - n0);
  char* hsb = (char*)hs;
  char* wsb = (char*)WsT;

  #pragma unroll
  for (int u = 0; u < 8; ++u) {
    const int i = tid + 256 * u;
    const int r = i >> 4, k8 = (i & 15) << 3;
    uint4 v = make_uint4(0u, 0u, 0u, 0u);
    if (r < rows) v = *(const uint4*)(A + (size_t)(n0 + r) * lda + k8);
    *(uint4*)(hsb + ((r * 256 + k8 * 2) ^ ((r & 7) << 4))) = v;
  }
  #pragma unroll
  for (int u = 0; u < 8; ++u) {
    const int i = tid + 256 * u;
    const int nn = i >> 4, k8 = (i & 15) << 3;
    const uint4 v = *(const uint4*)(WT + nn * 128 + k8);
    *(uint4*)(wsb + ((nn * 256 + k8 * 2) ^ ((nn & 7) << 4))) = v;
  }
  __syncthreads();

  const int l = tid & 63;
  const int m0 = (tid >> 6) << 5;
  const int lm = l & 31;
  const int lk = (l >> 5) << 3;
  const int ra = m0 + lm;
  f32x16 acc[4];
  #pragma unroll
  for (int t = 0; t < 4; ++t)
    #pragma unroll
    for (int q = 0; q < 16; ++q) acc[t][q] = 0.f;

  #pragma unroll
  for (int ks = 0; ks < 8; ++ks) {
    const int kb = (ks * 16 + lk) * 2;
    const bf16x8 af = *(const bf16x8*)(hsb + ((ra * 256 + kb) ^ ((ra & 7) << 4)));
    #pragma unroll
    for (int t = 0; t < 4; ++t) {
      const int rb = t * 32 + lm;
      const bf16x8 bfr = *(const bf16x8*)(wsb + ((rb * 256 + kb) ^ ((rb & 7) << 4)));
      acc[t] = __builtin_amdgcn_mfma_f32_32x32x16_bf16(af, bfr, acc[t], 0, 0, 0);
    }
  }

  #pragma unroll
  for (int t = 0; t < 4; ++t) {
    #pragma unroll
    for (int q = 0; q < 16; ++q) {
      const int m = m0 + (q & 3) + ((q >> 2) << 3) + ((l >> 5) << 2);
      if (m < rows) hw[(size_t)(n0 + m) * 128 + t * 32 + lm] = f2bf(acc[t][q]);
    }
  }
}

// ---- MFMA final: out = hcat(bf16) @ Wlin + blin, 3 K-chunks of 128 --------
__global__ __launch_bounds__(256, 2) void k_final_mfma(
    const unsigned short* __restrict__ hcat, const unsigned short* __restrict__ WTL,
    const float* __restrict__ blin, float* __restrict__ out, int N) {
  __shared__ __align__(16) unsigned short hs[128 * 128];
  __shared__ __align__(16) unsigned short WsT[64 * 128];
  const int tid = threadIdx.x;
  const int n0 = blockIdx.x * 128;
  const int rows = min(128, N - n0);
  char* hsb = (char*)hs;
  char* wsb = (char*)WsT;

  const int l = tid & 63;
  const int m0 = (tid >> 6) << 5;
  const int lm = l & 31;
  const int lk = (l >> 5) << 3;
  const int ra = m0 + lm;
  f32x16 acc[2];
  #pragma unroll
  for (int t = 0; t < 2; ++t)
    #pragma unroll
    for (int q = 0; q < 16; ++q) acc[t][q] = 0.f;

  for (int kc = 0; kc < 384; kc += 128) {
    #pragma unroll
    for (int u = 0; u < 8; ++u) {
      const int i = tid + 256 * u;
      const int r = i >> 4, k8 = (i & 15) << 3;
      uint4 v = make_uint4(0u, 0u, 0u, 0u);
      if (r < rows) v = *(const uint4*)(hcat + (size_t)(n0 + r) * 384 + kc + k8);
      *(uint4*)(hsb + ((r * 256 + k8 * 2) ^ ((r & 7) << 4))) = v;
    }
    #pragma unroll
    for (int u = 0; u < 4; ++u) {
      const int i = tid + 256 * u;
      const int nn = i >> 4, k8 = (i & 15) << 3;
      const uint4 v = *(const uint4*)(WTL + nn * 384 + kc + k8);
      *(uint4*)(wsb + ((nn * 256 + k8 * 2) ^ ((nn & 7) << 4))) = v;
    }
    __syncthreads();

    #pragma unroll
    for (int ks = 0; ks < 8; ++ks) {
      const int kb = (ks * 16 + lk) * 2;
      const bf16x8 af = *(const bf16x8*)(hsb + ((ra * 256 + kb) ^ ((ra & 7) << 4)));
      #pragma unroll
      for (int t = 0; t < 2; ++t) {
        const int rb = t * 32 + lm;
        const bf16x8 bfr = *(const bf16x8*)(wsb + ((rb * 256 + kb) ^ ((rb & 7) << 4)));
        acc[t] = __builtin_amdgcn_mfma_f32_32x32x16_bf16(af, bfr, acc[t], 0, 0, 0);
      }
    }
    __syncthreads();
  }

  #pragma unroll
  for (int t = 0; t < 2; ++t) {
    const float bb = blin[t * 32 + lm];
    #pragma unroll
    for (int q = 0; q < 16; ++q) {
      const int m = m0 + (q & 3) + ((q >> 2) << 3) + ((l >> 5) << 2);
      if (m < rows) out[(size_t)(n0 + m) * 64 + t * 32 + lm] = acc[t][q] + bb;
    }
  }
}

// ---- segment aggregate (32 lanes/node, ushort4/lane, 8-deep gather) -------
__global__ __launch_bounds__(256) void k_agg(
    const int* __restrict__ offs, const int* __restrict__ degi,
    const int* __restrict__ sorted_row, const float* __restrict__ dinv,
    const unsigned short* __restrict__ hw, const float* __restrict__ bias,
    unsigned short* __restrict__ hcat, int koff, int N) {
  const int g = (int)((blockIdx.x * 256 + threadIdx.x) >> 5);
  if (g >= N) return;
  const int j = (threadIdx.x & 31) << 2;
  const float dc = dinv[g];
  float acc[4];
  {
    const uint2 sv = *(const uint2*)(hw + (size_t)g * 128 + j);
    float f[4];
    bf4_unpack(sv, f);
    #pragma unroll
    for (int q = 0; q < 4; ++q) acc[q] = dc * f[q];
  }

  const int off = offs[g];
  const int end = off + degi[g];
  int e = off;
  for (; e + 7 < end; e += 8) {
    int r[8];
    #pragma unroll
    for (int t = 0; t < 8; ++t) r[t] = sorted_row[e + t];
    float dr[8];
    uint2 v[8];
    #pragma unroll
    for (int t = 0; t < 8; ++t) {
      dr[t] = dinv[r[t]];
      v[t] = *(const uint2*)(hw + (size_t)r[t] * 128 + j);
    }
    #pragma unroll
    for (int t = 0; t < 8; ++t) {
      float f[4];
      bf4_unpack(v[t], f);
      #pragma unroll
      for (int q = 0; q < 4; ++q) acc[q] = fmaf(dr[t], f[q], acc[q]);
    }
  }
  for (; e + 3 < end; e += 4) {
    int r[4];
    #pragma unroll
    for (int t = 0; t < 4; ++t) r[t] = sorted_row[e + t];
    float dr[4];
    uint2 v[4];
    #pragma unroll
    for (int t = 0; t < 4; ++t) {
      dr[t] = dinv[r[t]];
      v[t] = *(const uint2*)(hw + (size_t)r[t] * 128 + j);
    }
    #pragma unroll
    for (int t = 0; t < 4; ++t) {
      float f[4];
      bf4_unpack(v[t], f);
      #pragma unroll
      for (int q = 0; q < 4; ++q) acc[q] = fmaf(dr[t], f[q], acc[q]);
    }
  }
  for (; e < end; ++e) {
    const int r0 = sorted_row[e];
    const float d0 = dinv[r0];
    const uint2 v0 = *(const uint2*)(hw + (size_t)r0 * 128 + j);
    float f[4];
    bf4_unpack(v0, f);
    #pragma unroll
    for (int q = 0; q < 4; ++q) acc[q] = fmaf(d0, f[q], acc[q]);
  }

  const float4 bb = *(const float4*)(bias + j);
  const float o0 = fmaxf(fmaf(dc, acc[0], bb.x), 0.f);
  const float o1 = fmaxf(fmaf(dc, acc[1], bb.y), 0.f);
  const float o2 = fmaxf(fmaf(dc, acc[2], bb.z), 0.f);
  const float o3 = fmaxf(fmaf(dc, acc[3], bb.w), 0.f);
  uint2 st;
  st.x = bfpack(o0, o1);
  st.y = bfpack(o2, o3);
  *(uint2*)(hcat + (size_t)g * 384 + koff + j) = st;
}

extern "C" void kernel_launch(void* const* d_in, const int* in_sizes, int n_in,
                              void* d_out, int out_size, void* d_ws, size_t ws_size,
                              hipStream_t stream) {
  const float* x    = (const float*)d_in[0];
  const int*   ei   = (const int*)d_in[1];
  const float* W1   = (const float*)d_in[2];
  const float* b1   = (const float*)d_in[3];
  const float* W2   = (const float*)d_in[4];
  const float* b2   = (const float*)d_in[5];
  const float* W3   = (const float*)d_in[6];
  const float* b3   = (const float*)d_in[7];
  const float* Wlin = (const float*)d_in[8];
  const float* blin = (const float*)d_in[9];

  const int N = in_sizes[0] / 128;
  const int E = in_sizes[1] / 2;
  const int* rowi = ei;
  const int* coli = ei + E;

  // ws: degi|dinv|offs|cursor|bsums|sorted_row|WT1|WT2|WT3|WTL|xb|hw|hcat
  char* ws = (char*)d_ws;
  const size_t nb4 = (((size_t)N * 4) + 255) & ~(size_t)255;
  int*   degi       = (int*)ws;                 ws += nb4;
  float* dinv       = (float*)ws;               ws += nb4;
  int*   offs       = (int*)ws;                 ws += nb4;
  int*   cursor     = (int*)ws;                 ws += nb4;
  int*   bsums      = (int*)ws;                 ws += 1024;
  int*   sorted_row = (int*)ws;                 ws += (((size_t)E * 4) + 255) & ~(size_t)255;
  unsigned short* WT1  = (unsigned short*)ws;   ws += 128 * 128 * 2;
  unsigned short* WT2  = (unsigned short*)ws;   ws += 128 * 128 * 2;
  unsigned short* WT3  = (unsigned short*)ws;   ws += 128 * 128 * 2;
  unsigned short* WTL  = (unsigned short*)ws;   ws += 64 * 384 * 2;
  unsigned short* xb   = (unsigned short*)ws;   ws += (size_t)N * 128 * 2;
  unsigned short* hw   = (unsigned short*)ws;   ws += (size_t)N * 128 * 2;
  unsigned short* hcat = (unsigned short*)ws;

  const int nblk = (N + 1023) / 1024;
  const int gemmBlocks = (N + 127) / 128;
  const int convBlocks = (int)(((long long)N * 128 / 8 + 255) / 256);
  const int degBlocks  = (E + 2047) / 2048;
  const int fillBlocks = (E + 1023) / 1024;
  const int aggBlocks  = (N + 7) / 8;

  k_wt<<<(49152 + 24576 + 255) / 256, 256, 0, stream>>>(W1, W2, W3, Wlin,
                                                        WT1, WT2, WT3, WTL);
  hipMemsetAsync(degi, 0, (size_t)N * 4, stream);
  k_mega0<<<convBlocks + degBlocks, 256, 0, stream>>>(x, xb, N, convBlocks,
                                                      coli, E, degi);
  k_scan1<<<nblk, 256, 0, stream>>>(degi, N, offs, bsums, dinv);
  k_scan2<<<1, 128, 0, stream>>>(bsums, nblk);
  k_scan3<<<nblk, 256, 0, stream>>>(offs, bsums, cursor, N);
  k_mega1<<<gemmBlocks + fillBlocks, 256, 0, stream>>>(xb, WT1, hw, N, gemmBlocks,
                                                       rowi, coli, cursor,
                                                       sorted_row, E);

  k_agg<<<aggBlocks, 256, 0, stream>>>(offs, degi, sorted_row, dinv, hw,
                                       b1, hcat, 0, N);
  k_gemm_mfma<<<gemmBlocks, 256, 0, stream>>>(hcat, 384, WT2, hw, N);
  k_agg<<<aggBlocks, 256, 0, stream>>>(offs, degi, sorted_row, dinv, hw,
                                       b2, hcat, 128, N);
  k_gemm_mfma<<<gemmBlocks, 256, 0, stream>>>(hcat + 128, 384, WT3, hw, N);
  k_agg<<<aggBlocks, 256, 0, stream>>>(offs, degi, sorted_row, dinv, hw,
                                       b3, hcat, 256, N);
  k_final_mfma<<<gemmBlocks, 256, 0, stream>>>(hcat, WTL, blin, (float*)d_out, N);
}